// Round 3
// baseline (8873.191 us; speedup 1.0000x reference)
//
#include <hip/hip_runtime.h>
#include <hip/hip_bf16.h>
#include <math.h>

// Problem constants
#define BB   64
#define SS   1024
#define S1C  1025
#define DD   64
#define NHD  4
#define DHD  16
#define DFFC 256
#define NLAY 3
#define NTOK (BB * S1C)

typedef const float* fp;

__device__ __forceinline__ float gelu_exact(float x) {
    return 0.5f * x * (1.0f + erff(x * 0.7071067811865475f));
}

// ---------------------------------------------------------------------------
// Kernel 1: encoder MLP (1->48 GELU -> 64) + sos concat + positional encoding
// one block (64 threads) per token (b, s) with s in [0, S1)
// ---------------------------------------------------------------------------
__global__ __launch_bounds__(64) void k_encode(
    fp in_seq, fp enc_w1, fp enc_b1, fp enc_w2, fp enc_b2, fp sos,
    float* __restrict__ x)
{
    int tok = blockIdx.x;
    int b = tok / S1C, s = tok % S1C;
    int d = threadIdx.x;                 // 0..63
    __shared__ float e[48];
    float val;
    if (s == 0) {
        val = sos[d];
    } else {
        float t = in_seq[b * SS + (s - 1)];
        if (d < 48) e[d] = gelu_exact(t * enc_w1[d] + enc_b1[d]);
        __syncthreads();
        float acc = enc_b2[d];
        for (int j = 0; j < 48; ++j) acc += e[j] * enc_w2[j * DD + d];
        val = acc;
    }
    // positional encoding: pe[s, 2i] = sin(s*div_i), pe[s, 2i+1] = cos(s*div_i)
    int i2 = (d >> 1) * 2;
    float factor = expf((float)i2 * (-9.210340371976184f / 64.0f)); // -ln(10000)/D
    float ang = (float)s * factor;
    val += (d & 1) ? cosf(ang) : sinf(ang);
    x[(size_t)tok * DD + d] = val;
}

// ---------------------------------------------------------------------------
// Kernel 2: fused Q/K/V projection (3x 64x64 matmul + bias), one block/token.
// Writes q,k,v in [b][h][s][e] layout for attention coalescing.
// ---------------------------------------------------------------------------
__global__ __launch_bounds__(64) void k_qkv(
    const float* __restrict__ x,
    fp wq, fp wk, fp wv, fp bq, fp bk, fp bv,
    float* __restrict__ q, float* __restrict__ k, float* __restrict__ v)
{
    int tok = blockIdx.x;
    int b = tok / S1C, s = tok % S1C;
    int d = threadIdx.x;
    __shared__ float xs[DD];
    xs[d] = x[(size_t)tok * DD + d];
    __syncthreads();
    float aq = bq[d], ak = bk[d], av = bv[d];
    for (int j = 0; j < DD; ++j) {
        float xv = xs[j];
        aq += xv * wq[j * DD + d];
        ak += xv * wk[j * DD + d];
        av += xv * wv[j * DD + d];
    }
    int h = d >> 4, ee = d & 15;
    size_t idx = (((size_t)(b * NHD + h)) * S1C + s) * DHD + ee;
    q[idx] = aq; k[idx] = ak; v[idx] = av;
}

// ---------------------------------------------------------------------------
// Kernel 3: flash-row attention. One block (256 thr) per (b, h, query row).
// Scores (1025) live in LDS; softmax with max-subtraction; PV via 16x16
// thread grouping.
// ---------------------------------------------------------------------------
__global__ __launch_bounds__(256) void k_attn(
    const float* __restrict__ q, const float* __restrict__ k,
    const float* __restrict__ v, float* __restrict__ o)
{
    int bid = blockIdx.x;           // b*NHD*S1 + h*S1 + qi
    int qi  = bid % S1C;
    int bh  = bid / S1C;            // b*NHD + h
    int b   = bh / NHD, h = bh % NHD;
    int tid = threadIdx.x;

    __shared__ float qrow[DHD];
    __shared__ float sc[S1C];
    __shared__ float red[256];
    __shared__ float part[16 * DHD];

    const float* qptr = q + ((size_t)bh * S1C + qi) * DHD;
    if (tid < DHD) qrow[tid] = qptr[tid];
    __syncthreads();

    const float* kbase = k + (size_t)bh * S1C * DHD;
    float lmax = -1e30f;
    for (int kk = tid; kk < S1C; kk += 256) {
        const float* kp = kbase + (size_t)kk * DHD;
        float acc = 0.f;
        #pragma unroll
        for (int e = 0; e < DHD; ++e) acc += qrow[e] * kp[e];
        acc *= 0.25f;                 // 1/sqrt(16)
        sc[kk] = acc;
        lmax = fmaxf(lmax, acc);
    }
    red[tid] = lmax;
    __syncthreads();
    for (int st = 128; st > 0; st >>= 1) {
        if (tid < st) red[tid] = fmaxf(red[tid], red[tid + st]);
        __syncthreads();
    }
    float m = red[0];
    __syncthreads();

    float lsum = 0.f;
    for (int kk = tid; kk < S1C; kk += 256) {
        float ev = expf(sc[kk] - m);
        sc[kk] = ev;
        lsum += ev;
    }
    red[tid] = lsum;
    __syncthreads();
    for (int st = 128; st > 0; st >>= 1) {
        if (tid < st) red[tid] += red[tid + st];
        __syncthreads();
    }
    float denom = red[0];

    // PV: 16 groups of 16 threads; group g strides keys, lane e is head dim
    int g = tid >> 4, e = tid & 15;
    const float* vbase = v + (size_t)bh * S1C * DHD;
    float acc = 0.f;
    for (int kk = g; kk < S1C; kk += 16) acc += sc[kk] * vbase[(size_t)kk * DHD + e];
    part[g * DHD + e] = acc;
    __syncthreads();
    if (tid < DHD) {
        float s = 0.f;
        #pragma unroll
        for (int gg = 0; gg < 16; ++gg) s += part[gg * DHD + tid];
        o[((size_t)b * S1C + qi) * DD + h * DHD + tid] = s / denom;
    }
}

// ---------------------------------------------------------------------------
// Kernel 4: out-projection + residual + LayerNorm1. One wave (64 thr)/token.
// ---------------------------------------------------------------------------
__global__ __launch_bounds__(64) void k_oproj_ln(
    const float* __restrict__ o, float* __restrict__ x,
    fp wo, fp bo, fp lns, fp lnb)
{
    int tok = blockIdx.x;
    int d = threadIdx.x;
    __shared__ float os[DD];
    os[d] = o[(size_t)tok * DD + d];
    __syncthreads();
    float acc = bo[d];
    for (int j = 0; j < DD; ++j) acc += os[j] * wo[j * DD + d];
    float t = acc + x[(size_t)tok * DD + d];
    float sum = t;
    for (int off = 32; off > 0; off >>= 1) sum += __shfl_xor(sum, off, 64);
    float mean = sum * (1.0f / 64.0f);
    float c = t - mean;
    float vs = c * c;
    for (int off = 32; off > 0; off >>= 1) vs += __shfl_xor(vs, off, 64);
    float var = vs * (1.0f / 64.0f);
    float y = c / sqrtf(var + 1e-5f) * lns[d] + lnb[d];
    x[(size_t)tok * DD + d] = y;
}

// ---------------------------------------------------------------------------
// Kernel 5: FFN (64 -> 256 GELU -> 64) + residual + LayerNorm2.
// 256 threads per token; final LN on wave 0 (threads 0..63).
// ---------------------------------------------------------------------------
__global__ __launch_bounds__(256) void k_ffn_ln(
    float* __restrict__ x,
    fp w1, fp b1, fp w2, fp b2, fp lns, fp lnb)
{
    int tok = blockIdx.x;
    int tid = threadIdx.x;
    __shared__ float xs[DD];
    __shared__ float hid[DFFC];
    if (tid < DD) xs[tid] = x[(size_t)tok * DD + tid];
    __syncthreads();
    float acc = b1[tid];
    for (int j = 0; j < DD; ++j) acc += xs[j] * w1[j * DFFC + tid];
    hid[tid] = gelu_exact(acc);
    __syncthreads();
    if (tid < DD) {
        float f = b2[tid];
        for (int t = 0; t < DFFC; ++t) f += hid[t] * w2[t * DD + tid];
        float val = xs[tid] + f;
        float sum = val;
        for (int off = 32; off > 0; off >>= 1) sum += __shfl_xor(sum, off, 64);
        float mean = sum * (1.0f / 64.0f);
        float c = val - mean;
        float vs = c * c;
        for (int off = 32; off > 0; off >>= 1) vs += __shfl_xor(vs, off, 64);
        float y = c / sqrtf(vs * (1.0f / 64.0f) + 1e-5f) * lns[tid] + lnb[tid];
        x[(size_t)tok * DD + tid] = y;
    }
}

// ---------------------------------------------------------------------------
// Kernel 6: head MLPs. One block (64 thr) per batch element.
// ---------------------------------------------------------------------------
__global__ __launch_bounds__(64) void k_head(
    const float* __restrict__ x, fp proj_vars, fp param_vars,
    const int* __restrict__ materials,
    fp pw1, fp pb1, fp pw2, fp pb2, fp pw3, fp pb3,
    fp pw4, fp pb4, fp pw5, fp pb5,
    fp ipw1, fp ipb1, fp ipw2, fp ipb2,
    fp hw1, fp hb1, fp hw2, fp hb2, fp hw3, fp hb3,
    float* __restrict__ out)
{
    int b = blockIdx.x;
    int tid = threadIdx.x;      // 64 threads
    __shared__ float A[80], Bf[80], pp[8], mi[32];

    if (tid < 3) A[tid] = proj_vars[b * 3 + tid];
    A[3 + tid] = x[((size_t)b * S1C + 0) * DD + tid];   // sos_out
    __syncthreads();

    if (tid < 34) {            // 67 -> 34, gelu
        float a = pb1[tid];
        for (int i = 0; i < 67; ++i) a += A[i] * pw1[i * 34 + tid];
        Bf[tid] = gelu_exact(a);
    }
    __syncthreads();
    if (tid < 11) {            // 34 -> 11, gelu
        float a = pb2[tid];
        for (int i = 0; i < 34; ++i) a += Bf[i] * pw2[i * 11 + tid];
        A[tid] = gelu_exact(a);
    }
    __syncthreads();
    if (tid < 36) {            // 11 -> 36, gelu
        float a = pb3[tid];
        for (int i = 0; i < 11; ++i) a += A[i] * pw3[i * 36 + tid];
        Bf[tid] = gelu_exact(a);
    }
    __syncthreads();
    if (tid < 22) {            // 36 -> 22, gelu
        float a = pb4[tid];
        for (int i = 0; i < 36; ++i) a += Bf[i] * pw4[i * 22 + tid];
        A[tid] = gelu_exact(a);
    }
    __syncthreads();
    if (tid < 24) {            // 22 -> 24, linear -> proj_out -> mi[3..26]
        float a = pb5[tid];
        for (int i = 0; i < 22; ++i) a += A[i] * pw5[i * 24 + tid];
        mi[3 + tid] = a;
    }
    if (tid < 3) {             // param path stage 1: 3 -> 3, gelu
        float a = ipb1[tid];
        for (int i = 0; i < 3; ++i) a += param_vars[b * 3 + i] * ipw1[i * 3 + tid];
        pp[tid] = gelu_exact(a);
    }
    __syncthreads();
    if (tid < 3) {             // param path stage 2: 3 -> 3, linear -> mi[0..2]
        float a = ipb2[tid];
        for (int i = 0; i < 3; ++i) a += pp[i] * ipw2[i * 3 + tid];
        mi[tid] = a;
    }
    __syncthreads();

    int m = materials[b];
    if (tid < 15) {            // 27 -> 15, gelu
        float a = hb1[m * 15 + tid];
        for (int i = 0; i < 27; ++i) a += mi[i] * hw1[(m * 27 + i) * 15 + tid];
        A[tid] = gelu_exact(a);
    }
    __syncthreads();
    if (tid < 18) {            // 15 -> 18, gelu
        float a = hb2[m * 18 + tid];
        for (int i = 0; i < 15; ++i) a += A[i] * hw2[(m * 15 + i) * 18 + tid];
        Bf[tid] = gelu_exact(a);
    }
    __syncthreads();
    if (tid == 0) {            // 18 -> 1, linear
        float a = hb3[m];
        for (int i = 0; i < 18; ++i) a += Bf[i] * hw3[m * 18 + i];
        out[b] = a;
    }
}

// ---------------------------------------------------------------------------
extern "C" void kernel_launch(void* const* d_in, const int* in_sizes, int n_in,
                              void* d_out, int out_size, void* d_ws, size_t ws_size,
                              hipStream_t stream) {
    fp in_seq     = (fp)d_in[0];
    fp proj_vars  = (fp)d_in[1];
    fp param_vars = (fp)d_in[2];
    const int* materials = (const int*)d_in[3];
    fp enc_w1 = (fp)d_in[4];
    fp enc_b1 = (fp)d_in[5];
    fp enc_w2 = (fp)d_in[6];
    fp enc_b2 = (fp)d_in[7];
    fp sos    = (fp)d_in[8];
    fp tl_wq  = (fp)d_in[9];
    fp tl_wk  = (fp)d_in[10];
    fp tl_wv  = (fp)d_in[11];
    fp tl_bq  = (fp)d_in[12];
    fp tl_bk  = (fp)d_in[13];
    fp tl_bv  = (fp)d_in[14];
    fp tl_wo  = (fp)d_in[15];
    fp tl_bo  = (fp)d_in[16];
    fp tl_ln1s = (fp)d_in[17];
    fp tl_ln1b = (fp)d_in[18];
    fp tl_ln2s = (fp)d_in[19];
    fp tl_ln2b = (fp)d_in[20];
    fp tl_fw1 = (fp)d_in[21];
    fp tl_fb1 = (fp)d_in[22];
    fp tl_fw2 = (fp)d_in[23];
    fp tl_fb2 = (fp)d_in[24];
    fp pw1 = (fp)d_in[25]; fp pb1 = (fp)d_in[26];
    fp pw2 = (fp)d_in[27]; fp pb2 = (fp)d_in[28];
    fp pw3 = (fp)d_in[29]; fp pb3 = (fp)d_in[30];
    fp pw4 = (fp)d_in[31]; fp pb4 = (fp)d_in[32];
    fp pw5 = (fp)d_in[33]; fp pb5 = (fp)d_in[34];
    fp ipw1 = (fp)d_in[35]; fp ipb1 = (fp)d_in[36];
    fp ipw2 = (fp)d_in[37]; fp ipb2 = (fp)d_in[38];
    fp hw1 = (fp)d_in[39]; fp hb1 = (fp)d_in[40];
    fp hw2 = (fp)d_in[41]; fp hb2 = (fp)d_in[42];
    fp hw3 = (fp)d_in[43]; fp hb3 = (fp)d_in[44];

    // Workspace layout (fp32): x, q, k, v, o — each NTOK*DD floats (16.8 MB)
    float* x = (float*)d_ws;
    float* q = x + (size_t)NTOK * DD;
    float* k = q + (size_t)NTOK * DD;
    float* v = k + (size_t)NTOK * DD;
    float* o = v + (size_t)NTOK * DD;

    k_encode<<<NTOK, 64, 0, stream>>>(in_seq, enc_w1, enc_b1, enc_w2, enc_b2, sos, x);

    for (int l = 0; l < NLAY; ++l) {
        k_qkv<<<NTOK, 64, 0, stream>>>(
            x,
            tl_wq + (size_t)l * DD * DD, tl_wk + (size_t)l * DD * DD, tl_wv + (size_t)l * DD * DD,
            tl_bq + (size_t)l * DD, tl_bk + (size_t)l * DD, tl_bv + (size_t)l * DD,
            q, k, v);
        k_attn<<<BB * NHD * S1C, 256, 0, stream>>>(q, k, v, o);
        k_oproj_ln<<<NTOK, 64, 0, stream>>>(
            o, x,
            tl_wo + (size_t)l * DD * DD, tl_bo + (size_t)l * DD,
            tl_ln1s + (size_t)l * DD, tl_ln1b + (size_t)l * DD);
        k_ffn_ln<<<NTOK, 256, 0, stream>>>(
            x,
            tl_fw1 + (size_t)l * DD * DFFC, tl_fb1 + (size_t)l * DFFC,
            tl_fw2 + (size_t)l * DFFC * DD, tl_fb2 + (size_t)l * DD,
            tl_ln2s + (size_t)l * DD, tl_ln2b + (size_t)l * DD);
    }

    k_head<<<BB, 64, 0, stream>>>(
        x, proj_vars, param_vars, materials,
        pw1, pb1, pw2, pb2, pw3, pb3, pw4, pb4, pw5, pb5,
        ipw1, ipb1, ipw2, ipb2,
        hw1, hb1, hw2, hb2, hw3, hb3,
        (float*)d_out);
}

// Round 4
// 7187.980 us; speedup vs baseline: 1.2344x; 1.2344x over previous
//
#include <hip/hip_runtime.h>
#include <hip/hip_bf16.h>
#include <math.h>

// Problem constants
#define BB   64
#define SS   1024
#define S1C  1025
#define DD   64
#define NHD  4
#define DHD  16
#define DFFC 256
#define NLAY 3
#define NTOK (BB * S1C)
#define QTILES 65   // ceil(1025/16)

typedef const float* fp;

__device__ __forceinline__ float gelu_exact(float x) {
    return 0.5f * x * (1.0f + erff(x * 0.7071067811865475f));
}

__device__ __forceinline__ float dot16(const float4 qa, const float4 qb,
                                       const float4 qc, const float4 qd,
                                       const float4* __restrict__ kp)
{
    float4 ka = kp[0], kb = kp[1], kc = kp[2], kd = kp[3];
    float acc;
    acc  = qa.x * ka.x + qa.y * ka.y + qa.z * ka.z + qa.w * ka.w;
    acc += qb.x * kb.x + qb.y * kb.y + qb.z * kb.z + qb.w * kb.w;
    acc += qc.x * kc.x + qc.y * kc.y + qc.z * kc.z + qc.w * kc.w;
    acc += qd.x * kd.x + qd.y * kd.y + qd.z * kd.z + qd.w * kd.w;
    return acc;
}

// ---------------------------------------------------------------------------
// Kernel 1: encoder MLP (1->48 GELU -> 64) + sos concat + positional encoding
// ---------------------------------------------------------------------------
__global__ __launch_bounds__(64) void k_encode(
    fp in_seq, fp enc_w1, fp enc_b1, fp enc_w2, fp enc_b2, fp sos,
    float* __restrict__ x)
{
    int tok = blockIdx.x;
    int b = tok / S1C, s = tok % S1C;
    int d = threadIdx.x;                 // 0..63
    __shared__ float e[48];
    float val;
    if (s == 0) {
        val = sos[d];
    } else {
        float t = in_seq[b * SS + (s - 1)];
        if (d < 48) e[d] = gelu_exact(t * enc_w1[d] + enc_b1[d]);
        __syncthreads();
        float acc = enc_b2[d];
        for (int j = 0; j < 48; ++j) acc += e[j] * enc_w2[j * DD + d];
        val = acc;
    }
    int i2 = (d >> 1) * 2;
    float factor = expf((float)i2 * (-9.210340371976184f / 64.0f)); // -ln(10000)/D
    float ang = (float)s * factor;
    val += (d & 1) ? cosf(ang) : sinf(ang);
    x[(size_t)tok * DD + d] = val;
}

// ---------------------------------------------------------------------------
// Kernel 2: fused Q/K/V projection, one block/token. [bh][s][e] layout.
// ---------------------------------------------------------------------------
__global__ __launch_bounds__(64) void k_qkv(
    const float* __restrict__ x,
    fp wq, fp wk, fp wv, fp bq, fp bk, fp bv,
    float* __restrict__ q, float* __restrict__ k, float* __restrict__ v)
{
    int tok = blockIdx.x;
    int b = tok / S1C, s = tok % S1C;
    int d = threadIdx.x;
    __shared__ float xs[DD];
    xs[d] = x[(size_t)tok * DD + d];
    __syncthreads();
    float aq = bq[d], ak = bk[d], av = bv[d];
    for (int j = 0; j < DD; ++j) {
        float xv = xs[j];
        aq += xv * wq[j * DD + d];
        ak += xv * wk[j * DD + d];
        av += xv * wv[j * DD + d];
    }
    int h = d >> 4, ee = d & 15;
    size_t idx = (((size_t)(b * NHD + h)) * S1C + s) * DHD + ee;
    q[idx] = aq; k[idx] = ak; v[idx] = av;
}

// ---------------------------------------------------------------------------
// Kernel 3: register-resident attention.
// Block = 16 query rows of one (b,h). Thread (ql = t>>4, sk = t&15):
//   - holds scores for keys s = sk + 16*i (i = 0..63) plus the s=1024 tail
//     (owned by sk==0) entirely in VGPRs (preg[65])
//   - QK^T: float4 loads of k rows, 65 independent accumulators
//   - softmax: __shfl_xor reductions within the 16-lane group (no barriers)
//   - PV: 16 independent accumulators over e, float4 v-row loads
//   - single LDS transpose (16 KB) + one barrier for the cross-lane sum
// ---------------------------------------------------------------------------
__global__ __launch_bounds__(256) void k_attn(
    const float* __restrict__ q, const float* __restrict__ k,
    const float* __restrict__ v, float* __restrict__ o)
{
    int bid  = blockIdx.x;          // bh * QTILES + tile
    int tile = bid % QTILES;
    int bh   = bid / QTILES;
    int b    = bh >> 2, h = bh & 3;
    int t    = threadIdx.x;
    int ql   = t >> 4;              // local q row 0..15
    int sk   = t & 15;              // key lane
    int qg   = tile * 16 + ql;      // global q row
    int qld  = qg < S1C ? qg : (S1C - 1);

    const float4* q4 = (const float4*)(q + ((size_t)bh * S1C + qld) * DHD);
    float4 qa = q4[0], qb = q4[1], qc = q4[2], qd = q4[3];

    const float4* k4 = (const float4*)(k + (size_t)bh * S1C * DHD);
    const float4* v4 = (const float4*)(v + (size_t)bh * S1C * DHD);

    float preg[65];
    #pragma unroll
    for (int i = 0; i < 64; ++i) {
        int s = sk + 16 * i;
        preg[i] = dot16(qa, qb, qc, qd, k4 + (size_t)s * 4) * 0.25f;
    }
    {   // tail key s = 1024 — owned by sk == 0
        float tacc = dot16(qa, qb, qc, qd, k4 + (size_t)1024 * 4) * 0.25f;
        preg[64] = (sk == 0) ? tacc : -INFINITY;
    }

    // ---- softmax over the 16-lane group ----
    float m = preg[0];
    #pragma unroll
    for (int i = 1; i < 65; ++i) m = fmaxf(m, preg[i]);
    #pragma unroll
    for (int mask = 1; mask < 16; mask <<= 1) m = fmaxf(m, __shfl_xor(m, mask, 64));

    float ssum = 0.f;
    #pragma unroll
    for (int i = 0; i < 65; ++i) {
        float ev = __expf(preg[i] - m);
        preg[i] = ev;
        ssum += ev;
    }
    #pragma unroll
    for (int mask = 1; mask < 16; mask <<= 1) ssum += __shfl_xor(ssum, mask, 64);
    float inv = 1.0f / ssum;

    // ---- PV: accumulate o[ql][0..15] partials over this lane's keys ----
    float accv[16];
    #pragma unroll
    for (int e = 0; e < 16; ++e) accv[e] = 0.f;
    #pragma unroll
    for (int i = 0; i < 65; ++i) {
        int s = (i == 64) ? 1024 : (sk + 16 * i);   // tail: in-bounds load, p=0 for sk!=0
        float p = preg[i];
        const float4* vp = v4 + (size_t)s * 4;
        float4 va = vp[0], vb = vp[1], vc = vp[2], vd = vp[3];
        accv[ 0] += p * va.x; accv[ 1] += p * va.y; accv[ 2] += p * va.z; accv[ 3] += p * va.w;
        accv[ 4] += p * vb.x; accv[ 5] += p * vb.y; accv[ 6] += p * vb.z; accv[ 7] += p * vb.w;
        accv[ 8] += p * vc.x; accv[ 9] += p * vc.y; accv[10] += p * vc.z; accv[11] += p * vc.w;
        accv[12] += p * vd.x; accv[13] += p * vd.y; accv[14] += p * vd.z; accv[15] += p * vd.w;
    }

    // ---- cross-lane (sk) reduction via LDS transpose ----
    __shared__ float part[16][16][16];   // [ql][sk][e]
    float4* pw = (float4*)&part[ql][sk][0];
    pw[0] = make_float4(accv[ 0] * inv, accv[ 1] * inv, accv[ 2] * inv, accv[ 3] * inv);
    pw[1] = make_float4(accv[ 4] * inv, accv[ 5] * inv, accv[ 6] * inv, accv[ 7] * inv);
    pw[2] = make_float4(accv[ 8] * inv, accv[ 9] * inv, accv[10] * inv, accv[11] * inv);
    pw[3] = make_float4(accv[12] * inv, accv[13] * inv, accv[14] * inv, accv[15] * inv);
    __syncthreads();

    // remap: thread (ql, e = sk) sums over the 16 sk partials
    int e = sk;
    float s0 = 0.f;
    #pragma unroll
    for (int j = 0; j < 16; ++j) s0 += part[ql][j][e];
    if (qg < S1C)
        o[((size_t)b * S1C + qg) * DD + h * DHD + e] = s0;
}

// ---------------------------------------------------------------------------
// Kernel 4: out-projection + residual + LayerNorm1. One wave (64 thr)/token.
// ---------------------------------------------------------------------------
__global__ __launch_bounds__(64) void k_oproj_ln(
    const float* __restrict__ o, float* __restrict__ x,
    fp wo, fp bo, fp lns, fp lnb)
{
    int tok = blockIdx.x;
    int d = threadIdx.x;
    __shared__ float os[DD];
    os[d] = o[(size_t)tok * DD + d];
    __syncthreads();
    float acc = bo[d];
    for (int j = 0; j < DD; ++j) acc += os[j] * wo[j * DD + d];
    float t = acc + x[(size_t)tok * DD + d];
    float sum = t;
    for (int off = 32; off > 0; off >>= 1) sum += __shfl_xor(sum, off, 64);
    float mean = sum * (1.0f / 64.0f);
    float c = t - mean;
    float vs = c * c;
    for (int off = 32; off > 0; off >>= 1) vs += __shfl_xor(vs, off, 64);
    float var = vs * (1.0f / 64.0f);
    float y = c / sqrtf(var + 1e-5f) * lns[d] + lnb[d];
    x[(size_t)tok * DD + d] = y;
}

// ---------------------------------------------------------------------------
// Kernel 5: FFN (64 -> 256 GELU -> 64) + residual + LayerNorm2.
// ---------------------------------------------------------------------------
__global__ __launch_bounds__(256) void k_ffn_ln(
    float* __restrict__ x,
    fp w1, fp b1, fp w2, fp b2, fp lns, fp lnb)
{
    int tok = blockIdx.x;
    int tid = threadIdx.x;
    __shared__ float xs[DD];
    __shared__ float hid[DFFC];
    if (tid < DD) xs[tid] = x[(size_t)tok * DD + tid];
    __syncthreads();
    float acc = b1[tid];
    for (int j = 0; j < DD; ++j) acc += xs[j] * w1[j * DFFC + tid];
    hid[tid] = gelu_exact(acc);
    __syncthreads();
    if (tid < DD) {
        float f = b2[tid];
        for (int t = 0; t < DFFC; ++t) f += hid[t] * w2[t * DD + tid];
        float val = xs[tid] + f;
        float sum = val;
        for (int off = 32; off > 0; off >>= 1) sum += __shfl_xor(sum, off, 64);
        float mean = sum * (1.0f / 64.0f);
        float c = val - mean;
        float vs = c * c;
        for (int off = 32; off > 0; off >>= 1) vs += __shfl_xor(vs, off, 64);
        float y = c / sqrtf(vs * (1.0f / 64.0f) + 1e-5f) * lns[tid] + lnb[tid];
        x[(size_t)tok * DD + tid] = y;
    }
}

// ---------------------------------------------------------------------------
// Kernel 6: head MLPs. One block (64 thr) per batch element.
// ---------------------------------------------------------------------------
__global__ __launch_bounds__(64) void k_head(
    const float* __restrict__ x, fp proj_vars, fp param_vars,
    const int* __restrict__ materials,
    fp pw1, fp pb1, fp pw2, fp pb2, fp pw3, fp pb3,
    fp pw4, fp pb4, fp pw5, fp pb5,
    fp ipw1, fp ipb1, fp ipw2, fp ipb2,
    fp hw1, fp hb1, fp hw2, fp hb2, fp hw3, fp hb3,
    float* __restrict__ out)
{
    int b = blockIdx.x;
    int tid = threadIdx.x;      // 64 threads
    __shared__ float A[80], Bf[80], pp[8], mi[32];

    if (tid < 3) A[tid] = proj_vars[b * 3 + tid];
    A[3 + tid] = x[((size_t)b * S1C + 0) * DD + tid];   // sos_out
    __syncthreads();

    if (tid < 34) {
        float a = pb1[tid];
        for (int i = 0; i < 67; ++i) a += A[i] * pw1[i * 34 + tid];
        Bf[tid] = gelu_exact(a);
    }
    __syncthreads();
    if (tid < 11) {
        float a = pb2[tid];
        for (int i = 0; i < 34; ++i) a += Bf[i] * pw2[i * 11 + tid];
        A[tid] = gelu_exact(a);
    }
    __syncthreads();
    if (tid < 36) {
        float a = pb3[tid];
        for (int i = 0; i < 11; ++i) a += A[i] * pw3[i * 36 + tid];
        Bf[tid] = gelu_exact(a);
    }
    __syncthreads();
    if (tid < 22) {
        float a = pb4[tid];
        for (int i = 0; i < 36; ++i) a += Bf[i] * pw4[i * 22 + tid];
        A[tid] = gelu_exact(a);
    }
    __syncthreads();
    if (tid < 24) {
        float a = pb5[tid];
        for (int i = 0; i < 22; ++i) a += A[i] * pw5[i * 24 + tid];
        mi[3 + tid] = a;
    }
    if (tid < 3) {
        float a = ipb1[tid];
        for (int i = 0; i < 3; ++i) a += param_vars[b * 3 + i] * ipw1[i * 3 + tid];
        pp[tid] = gelu_exact(a);
    }
    __syncthreads();
    if (tid < 3) {
        float a = ipb2[tid];
        for (int i = 0; i < 3; ++i) a += pp[i] * ipw2[i * 3 + tid];
        mi[tid] = a;
    }
    __syncthreads();

    int m = materials[b];
    if (tid < 15) {
        float a = hb1[m * 15 + tid];
        for (int i = 0; i < 27; ++i) a += mi[i] * hw1[(m * 27 + i) * 15 + tid];
        A[tid] = gelu_exact(a);
    }
    __syncthreads();
    if (tid < 18) {
        float a = hb2[m * 18 + tid];
        for (int i = 0; i < 15; ++i) a += A[i] * hw2[(m * 15 + i) * 18 + tid];
        Bf[tid] = gelu_exact(a);
    }
    __syncthreads();
    if (tid == 0) {
        float a = hb3[m];
        for (int i = 0; i < 18; ++i) a += Bf[i] * hw3[m * 18 + i];
        out[b] = a;
    }
}

// ---------------------------------------------------------------------------
extern "C" void kernel_launch(void* const* d_in, const int* in_sizes, int n_in,
                              void* d_out, int out_size, void* d_ws, size_t ws_size,
                              hipStream_t stream) {
    fp in_seq     = (fp)d_in[0];
    fp proj_vars  = (fp)d_in[1];
    fp param_vars = (fp)d_in[2];
    const int* materials = (const int*)d_in[3];
    fp enc_w1 = (fp)d_in[4];
    fp enc_b1 = (fp)d_in[5];
    fp enc_w2 = (fp)d_in[6];
    fp enc_b2 = (fp)d_in[7];
    fp sos    = (fp)d_in[8];
    fp tl_wq  = (fp)d_in[9];
    fp tl_wk  = (fp)d_in[10];
    fp tl_wv  = (fp)d_in[11];
    fp tl_bq  = (fp)d_in[12];
    fp tl_bk  = (fp)d_in[13];
    fp tl_bv  = (fp)d_in[14];
    fp tl_wo  = (fp)d_in[15];
    fp tl_bo  = (fp)d_in[16];
    fp tl_ln1s = (fp)d_in[17];
    fp tl_ln1b = (fp)d_in[18];
    fp tl_ln2s = (fp)d_in[19];
    fp tl_ln2b = (fp)d_in[20];
    fp tl_fw1 = (fp)d_in[21];
    fp tl_fb1 = (fp)d_in[22];
    fp tl_fw2 = (fp)d_in[23];
    fp tl_fb2 = (fp)d_in[24];
    fp pw1 = (fp)d_in[25]; fp pb1 = (fp)d_in[26];
    fp pw2 = (fp)d_in[27]; fp pb2 = (fp)d_in[28];
    fp pw3 = (fp)d_in[29]; fp pb3 = (fp)d_in[30];
    fp pw4 = (fp)d_in[31]; fp pb4 = (fp)d_in[32];
    fp pw5 = (fp)d_in[33]; fp pb5 = (fp)d_in[34];
    fp ipw1 = (fp)d_in[35]; fp ipb1 = (fp)d_in[36];
    fp ipw2 = (fp)d_in[37]; fp ipb2 = (fp)d_in[38];
    fp hw1 = (fp)d_in[39]; fp hb1 = (fp)d_in[40];
    fp hw2 = (fp)d_in[41]; fp hb2 = (fp)d_in[42];
    fp hw3 = (fp)d_in[43]; fp hb3 = (fp)d_in[44];

    // Workspace layout (fp32): x, q, k, v, o — each NTOK*DD floats (16.8 MB)
    float* x = (float*)d_ws;
    float* q = x + (size_t)NTOK * DD;
    float* k = q + (size_t)NTOK * DD;
    float* v = k + (size_t)NTOK * DD;
    float* o = v + (size_t)NTOK * DD;

    k_encode<<<NTOK, 64, 0, stream>>>(in_seq, enc_w1, enc_b1, enc_w2, enc_b2, sos, x);

    for (int l = 0; l < NLAY; ++l) {
        k_qkv<<<NTOK, 64, 0, stream>>>(
            x,
            tl_wq + (size_t)l * DD * DD, tl_wk + (size_t)l * DD * DD, tl_wv + (size_t)l * DD * DD,
            tl_bq + (size_t)l * DD, tl_bk + (size_t)l * DD, tl_bv + (size_t)l * DD,
            q, k, v);
        k_attn<<<BB * NHD * QTILES, 256, 0, stream>>>(q, k, v, o);
        k_oproj_ln<<<NTOK, 64, 0, stream>>>(
            o, x,
            tl_wo + (size_t)l * DD * DD, tl_bo + (size_t)l * DD,
            tl_ln1s + (size_t)l * DD, tl_ln1b + (size_t)l * DD);
        k_ffn_ln<<<NTOK, 256, 0, stream>>>(
            x,
            tl_fw1 + (size_t)l * DD * DFFC, tl_fb1 + (size_t)l * DFFC,
            tl_fw2 + (size_t)l * DFFC * DD, tl_fb2 + (size_t)l * DD,
            tl_ln2s + (size_t)l * DD, tl_ln2b + (size_t)l * DD);
    }

    k_head<<<BB, 64, 0, stream>>>(
        x, proj_vars, param_vars, materials,
        pw1, pb1, pw2, pb2, pw3, pb3, pw4, pb4, pw5, pb5,
        ipw1, ipb1, ipw2, ipb2,
        hw1, hb1, hw2, hb2, hw3, hb3,
        (float*)d_out);
}

// Round 5
// 2229.001 us; speedup vs baseline: 3.9808x; 3.2248x over previous
//
#include <hip/hip_runtime.h>
#include <hip/hip_bf16.h>
#include <math.h>

// Problem constants
#define BB   64
#define SS   1024
#define S1C  1025
#define DD   64
#define NHD  4
#define DHD  16
#define DFFC 256
#define NLAY 3
#define NTOK (BB * S1C)
#define QTILES 65   // ceil(1025/16)
#define KTILE 128   // keys per LDS tile
#define NKT   8     // full tiles (1024 keys); key 1024 is the tail
#define KPAD  20    // kt row stride in floats (16 + 4): sk*20 mod 32 -> 2-way only
#define FTT   16    // tokens per k_ffn_ln block

typedef const float* fp;

__device__ __forceinline__ float gelu_exact(float x) {
    return 0.5f * x * (1.0f + erff(x * 0.7071067811865475f));
}

__device__ __forceinline__ float dot16r(const float4 qa, const float4 qb,
                                        const float4 qc, const float4 qd,
                                        const float* __restrict__ kp)
{
    float4 ka = *(const float4*)(kp);
    float4 kb = *(const float4*)(kp + 4);
    float4 kc = *(const float4*)(kp + 8);
    float4 kd = *(const float4*)(kp + 12);
    float acc;
    acc  = qa.x * ka.x + qa.y * ka.y + qa.z * ka.z + qa.w * ka.w;
    acc += qb.x * kb.x + qb.y * kb.y + qb.z * kb.z + qb.w * kb.w;
    acc += qc.x * kc.x + qc.y * kc.y + qc.z * kc.z + qc.w * kc.w;
    acc += qd.x * kd.x + qd.y * kd.y + qd.z * kd.z + qd.w * kd.w;
    return acc;
}

// ---------------------------------------------------------------------------
// Kernel 1: encoder MLP (1->48 GELU -> 64) + sos concat + positional encoding
// ---------------------------------------------------------------------------
__global__ __launch_bounds__(64) void k_encode(
    fp in_seq, fp enc_w1, fp enc_b1, fp enc_w2, fp enc_b2, fp sos,
    float* __restrict__ x)
{
    int tok = blockIdx.x;
    int b = tok / S1C, s = tok % S1C;
    int d = threadIdx.x;                 // 0..63
    __shared__ float e[48];
    float val;
    if (s == 0) {
        val = sos[d];
    } else {
        float t = in_seq[b * SS + (s - 1)];
        if (d < 48) e[d] = gelu_exact(t * enc_w1[d] + enc_b1[d]);
        __syncthreads();
        float acc = enc_b2[d];
        for (int j = 0; j < 48; ++j) acc += e[j] * enc_w2[j * DD + d];
        val = acc;
    }
    int i2 = (d >> 1) * 2;
    float factor = expf((float)i2 * (-9.210340371976184f / 64.0f)); // -ln(10000)/D
    float ang = (float)s * factor;
    val += (d & 1) ? cosf(ang) : sinf(ang);
    x[(size_t)tok * DD + d] = val;
}

// ---------------------------------------------------------------------------
// Kernel 2: fused Q/K/V projection, one block/token. [bh][s][e] layout.
// ---------------------------------------------------------------------------
__global__ __launch_bounds__(64) void k_qkv(
    const float* __restrict__ x,
    fp wq, fp wk, fp wv, fp bq, fp bk, fp bv,
    float* __restrict__ q, float* __restrict__ k, float* __restrict__ v)
{
    int tok = blockIdx.x;
    int b = tok / S1C, s = tok % S1C;
    int d = threadIdx.x;
    __shared__ float xs[DD];
    xs[d] = x[(size_t)tok * DD + d];
    __syncthreads();
    float aq = bq[d], ak = bk[d], av = bv[d];
    for (int j = 0; j < DD; ++j) {
        float xv = xs[j];
        aq += xv * wq[j * DD + d];
        ak += xv * wk[j * DD + d];
        av += xv * wv[j * DD + d];
    }
    int h = d >> 4, ee = d & 15;
    size_t idx = (((size_t)(b * NHD + h)) * S1C + s) * DHD + ee;
    q[idx] = aq; k[idx] = ak; v[idx] = av;
}

// ---------------------------------------------------------------------------
// Kernel 3: register-score attention with LDS-staged K/V tiles.
// Block = 16 q rows of one (b,h), 256 threads, thread (ql=t>>4, sk=t&15).
// Pass 1: for each 128-key tile, stage K in LDS (coalesced), compute 8
//         scores/thread from LDS (padded rows: 2-way bank alias only).
// Softmax: shuffle over the 16-lane sk group (no barriers).
// Pass 2: same tiling over V, 16 independent accumulators.
// Output: one LDS transpose + barrier.
// ---------------------------------------------------------------------------
__global__ __launch_bounds__(256) void k_attn(
    const float* __restrict__ q, const float* __restrict__ k,
    const float* __restrict__ v, float* __restrict__ o)
{
    int bid  = blockIdx.x;          // bh * QTILES + tile
    int tile = bid % QTILES;
    int bh   = bid / QTILES;
    int b    = bh >> 2, h = bh & 3;
    int t    = threadIdx.x;
    int ql   = t >> 4;              // local q row 0..15
    int sk   = t & 15;              // key lane
    int qg   = tile * 16 + ql;      // global q row
    int qld  = qg < S1C ? qg : (S1C - 1);

    const float4* q4 = (const float4*)(q + ((size_t)bh * S1C + qld) * DHD);
    float4 qa = q4[0], qb = q4[1], qc = q4[2], qd = q4[3];

    const float4* k4 = (const float4*)(k + (size_t)bh * S1C * DHD);
    const float4* v4 = (const float4*)(v + (size_t)bh * S1C * DHD);

    __shared__ float kt[KTILE * KPAD];        // 10 KB staging tile (K, then V)
    __shared__ float part[16 * 16 * 16];      // 16 KB output transpose

    float preg[NKT * 8 + 1];

    // ---- pass 1: QK^T ----
    for (int T = 0; T < NKT; ++T) {
        __syncthreads();   // previous tile consumers done
        {
            const float4* src = k4 + (size_t)T * KTILE * 4;
            int f0 = t, f1 = t + 256;
            float4 a = src[f0], bb2 = src[f1];
            *(float4*)&kt[(f0 >> 2) * KPAD + (f0 & 3) * 4] = a;
            *(float4*)&kt[(f1 >> 2) * KPAD + (f1 & 3) * 4] = bb2;
        }
        __syncthreads();
        #pragma unroll
        for (int j = 0; j < 8; ++j) {
            int srow = sk + 16 * j;
            preg[T * 8 + j] = dot16r(qa, qb, qc, qd, &kt[srow * KPAD]) * 0.25f;
        }
    }
    {   // tail key s = 1024 — owned by sk == 0
        float tacc = dot16r(qa, qb, qc, qd, (const float*)(k4 + (size_t)1024 * 4)) * 0.25f;
        preg[64] = (sk == 0) ? tacc : -INFINITY;
    }

    // ---- softmax over the 16-lane group ----
    float m = preg[0];
    #pragma unroll
    for (int i = 1; i < 65; ++i) m = fmaxf(m, preg[i]);
    #pragma unroll
    for (int mask = 1; mask < 16; mask <<= 1) m = fmaxf(m, __shfl_xor(m, mask, 64));

    float ssum = 0.f;
    #pragma unroll
    for (int i = 0; i < 65; ++i) {
        float ev = __expf(preg[i] - m);
        preg[i] = ev;
        ssum += ev;
    }
    #pragma unroll
    for (int mask = 1; mask < 16; mask <<= 1) ssum += __shfl_xor(ssum, mask, 64);
    float inv = 1.0f / ssum;

    // ---- pass 2: PV ----
    float accv[16];
    #pragma unroll
    for (int e = 0; e < 16; ++e) accv[e] = 0.f;

    for (int T = 0; T < NKT; ++T) {
        __syncthreads();
        {
            const float4* src = v4 + (size_t)T * KTILE * 4;
            int f0 = t, f1 = t + 256;
            float4 a = src[f0], bb2 = src[f1];
            *(float4*)&kt[(f0 >> 2) * KPAD + (f0 & 3) * 4] = a;
            *(float4*)&kt[(f1 >> 2) * KPAD + (f1 & 3) * 4] = bb2;
        }
        __syncthreads();
        #pragma unroll
        for (int j = 0; j < 8; ++j) {
            int srow = sk + 16 * j;
            float p = preg[T * 8 + j];
            const float* vp = &kt[srow * KPAD];
            float4 va = *(const float4*)(vp);
            float4 vb = *(const float4*)(vp + 4);
            float4 vc = *(const float4*)(vp + 8);
            float4 vd = *(const float4*)(vp + 12);
            accv[ 0] += p * va.x; accv[ 1] += p * va.y; accv[ 2] += p * va.z; accv[ 3] += p * va.w;
            accv[ 4] += p * vb.x; accv[ 5] += p * vb.y; accv[ 6] += p * vb.z; accv[ 7] += p * vb.w;
            accv[ 8] += p * vc.x; accv[ 9] += p * vc.y; accv[10] += p * vc.z; accv[11] += p * vc.w;
            accv[12] += p * vd.x; accv[13] += p * vd.y; accv[14] += p * vd.z; accv[15] += p * vd.w;
        }
    }
    {   // tail key s = 1024 (preg[64] == 0 for sk != 0)
        float p = preg[64];
        const float* vp = (const float*)(v4 + (size_t)1024 * 4);
        float4 va = *(const float4*)(vp);
        float4 vb = *(const float4*)(vp + 4);
        float4 vc = *(const float4*)(vp + 8);
        float4 vd = *(const float4*)(vp + 12);
        accv[ 0] += p * va.x; accv[ 1] += p * va.y; accv[ 2] += p * va.z; accv[ 3] += p * va.w;
        accv[ 4] += p * vb.x; accv[ 5] += p * vb.y; accv[ 6] += p * vb.z; accv[ 7] += p * vb.w;
        accv[ 8] += p * vc.x; accv[ 9] += p * vc.y; accv[10] += p * vc.z; accv[11] += p * vc.w;
        accv[12] += p * vd.x; accv[13] += p * vd.y; accv[14] += p * vd.z; accv[15] += p * vd.w;
    }

    // ---- cross-lane (sk) reduction via LDS transpose ----
    __syncthreads();   // kt consumers done (part overlaps nothing, but order writes)
    float* pw = &part[(ql * 16 + sk) * 16];
    *(float4*)(pw +  0) = make_float4(accv[ 0] * inv, accv[ 1] * inv, accv[ 2] * inv, accv[ 3] * inv);
    *(float4*)(pw +  4) = make_float4(accv[ 4] * inv, accv[ 5] * inv, accv[ 6] * inv, accv[ 7] * inv);
    *(float4*)(pw +  8) = make_float4(accv[ 8] * inv, accv[ 9] * inv, accv[10] * inv, accv[11] * inv);
    *(float4*)(pw + 12) = make_float4(accv[12] * inv, accv[13] * inv, accv[14] * inv, accv[15] * inv);
    __syncthreads();

    int e = sk;
    float s0 = 0.f;
    #pragma unroll
    for (int j = 0; j < 16; ++j) s0 += part[(ql * 16 + j) * 16 + e];
    if (qg < S1C)
        o[((size_t)b * S1C + qg) * DD + h * DHD + e] = s0;
}

// ---------------------------------------------------------------------------
// Kernel 4: out-projection + residual + LayerNorm1. One wave (64 thr)/token.
// ---------------------------------------------------------------------------
__global__ __launch_bounds__(64) void k_oproj_ln(
    const float* __restrict__ o, float* __restrict__ x,
    fp wo, fp bo, fp lns, fp lnb)
{
    int tok = blockIdx.x;
    int d = threadIdx.x;
    __shared__ float os[DD];
    os[d] = o[(size_t)tok * DD + d];
    __syncthreads();
    float acc = bo[d];
    for (int j = 0; j < DD; ++j) acc += os[j] * wo[j * DD + d];
    float t = acc + x[(size_t)tok * DD + d];
    float sum = t;
    for (int off = 32; off > 0; off >>= 1) sum += __shfl_xor(sum, off, 64);
    float mean = sum * (1.0f / 64.0f);
    float c = t - mean;
    float vs = c * c;
    for (int off = 32; off > 0; off >>= 1) vs += __shfl_xor(vs, off, 64);
    float var = vs * (1.0f / 64.0f);
    float y = c / sqrtf(var + 1e-5f) * lns[d] + lnb[d];
    x[(size_t)tok * DD + d] = y;
}

// ---------------------------------------------------------------------------
// Kernel 5: FFN (64 -> 256 GELU -> 64) + residual + LayerNorm2.
// 16 tokens/block, 256 threads. Weights held in registers, reused across the
// 16 tokens; LDS operands read as broadcast float4 (conflict-free).
// ---------------------------------------------------------------------------
__global__ __launch_bounds__(256) void k_ffn_ln(
    float* __restrict__ x,
    fp w1, fp b1, fp w2, fp b2, fp lns, fp lnb)
{
    int blk = blockIdx.x;
    int t = threadIdx.x;
    int tok0 = blk * FTT;
    __shared__ float xs[FTT][68];     // row stride 68 floats (16B multiple)
    __shared__ float hid[FTT][260];   // row stride 260 floats (16B multiple)

    #pragma unroll
    for (int i = 0; i < 4; ++i) {
        int idx = i * 256 + t;        // 0..1023
        xs[idx >> 6][idx & 63] = x[(size_t)tok0 * DD + idx];
    }
    __syncthreads();

    // phase 1: hid[tt][t] for all 16 tokens, dff = t
    {
        float acc[FTT];
        #pragma unroll
        for (int tt = 0; tt < FTT; ++tt) acc[tt] = 0.f;
        for (int j = 0; j < DD; j += 4) {
            float w0 = w1[(j + 0) * DFFC + t];
            float w1v = w1[(j + 1) * DFFC + t];
            float w2v = w1[(j + 2) * DFFC + t];
            float w3 = w1[(j + 3) * DFFC + t];
            #pragma unroll
            for (int tt = 0; tt < FTT; ++tt) {
                float4 xv = *(const float4*)&xs[tt][j];
                acc[tt] += xv.x * w0 + xv.y * w1v + xv.z * w2v + xv.w * w3;
            }
        }
        float b1v = b1[t];
        #pragma unroll
        for (int tt = 0; tt < FTT; ++tt) hid[tt][t] = gelu_exact(acc[tt] + b1v);
    }
    __syncthreads();

    // phase 2: wave w handles tokens w*4..w*4+3, dim d = lane
    int w = t >> 6, d = t & 63;
    float a2[4] = {0.f, 0.f, 0.f, 0.f};
    for (int kk = 0; kk < DFFC; kk += 4) {
        float w0 = w2[(kk + 0) * DD + d];
        float w1v = w2[(kk + 1) * DD + d];
        float w2v = w2[(kk + 2) * DD + d];
        float w3 = w2[(kk + 3) * DD + d];
        #pragma unroll
        for (int i = 0; i < 4; ++i) {
            float4 hv = *(const float4*)&hid[w * 4 + i][kk];
            a2[i] += hv.x * w0 + hv.y * w1v + hv.z * w2v + hv.w * w3;
        }
    }
    float b2v = b2[d], lnsv = lns[d], lnbv = lnb[d];
    #pragma unroll
    for (int i = 0; i < 4; ++i) {
        int tt = w * 4 + i;
        float val = xs[tt][d] + a2[i] + b2v;
        float sum = val;
        for (int off = 32; off > 0; off >>= 1) sum += __shfl_xor(sum, off, 64);
        float mean = sum * (1.0f / 64.0f);
        float c = val - mean;
        float vs = c * c;
        for (int off = 32; off > 0; off >>= 1) vs += __shfl_xor(vs, off, 64);
        float y = c / sqrtf(vs * (1.0f / 64.0f) + 1e-5f) * lnsv + lnbv;
        x[(size_t)(tok0 + tt) * DD + d] = y;
    }
}

// ---------------------------------------------------------------------------
// Kernel 6: head MLPs. One block (64 thr) per batch element.
// ---------------------------------------------------------------------------
__global__ __launch_bounds__(64) void k_head(
    const float* __restrict__ x, fp proj_vars, fp param_vars,
    const int* __restrict__ materials,
    fp pw1, fp pb1, fp pw2, fp pb2, fp pw3, fp pb3,
    fp pw4, fp pb4, fp pw5, fp pb5,
    fp ipw1, fp ipb1, fp ipw2, fp ipb2,
    fp hw1, fp hb1, fp hw2, fp hb2, fp hw3, fp hb3,
    float* __restrict__ out)
{
    int b = blockIdx.x;
    int tid = threadIdx.x;      // 64 threads
    __shared__ float A[80], Bf[80], pp[8], mi[32];

    if (tid < 3) A[tid] = proj_vars[b * 3 + tid];
    A[3 + tid] = x[((size_t)b * S1C + 0) * DD + tid];   // sos_out
    __syncthreads();

    if (tid < 34) {
        float a = pb1[tid];
        for (int i = 0; i < 67; ++i) a += A[i] * pw1[i * 34 + tid];
        Bf[tid] = gelu_exact(a);
    }
    __syncthreads();
    if (tid < 11) {
        float a = pb2[tid];
        for (int i = 0; i < 34; ++i) a += Bf[i] * pw2[i * 11 + tid];
        A[tid] = gelu_exact(a);
    }
    __syncthreads();
    if (tid < 36) {
        float a = pb3[tid];
        for (int i = 0; i < 11; ++i) a += A[i] * pw3[i * 36 + tid];
        Bf[tid] = gelu_exact(a);
    }
    __syncthreads();
    if (tid < 22) {
        float a = pb4[tid];
        for (int i = 0; i < 36; ++i) a += Bf[i] * pw4[i * 22 + tid];
        A[tid] = gelu_exact(a);
    }
    __syncthreads();
    if (tid < 24) {
        float a = pb5[tid];
        for (int i = 0; i < 22; ++i) a += A[i] * pw5[i * 24 + tid];
        mi[3 + tid] = a;
    }
    if (tid < 3) {
        float a = ipb1[tid];
        for (int i = 0; i < 3; ++i) a += param_vars[b * 3 + i] * ipw1[i * 3 + tid];
        pp[tid] = gelu_exact(a);
    }
    __syncthreads();
    if (tid < 3) {
        float a = ipb2[tid];
        for (int i = 0; i < 3; ++i) a += pp[i] * ipw2[i * 3 + tid];
        mi[tid] = a;
    }
    __syncthreads();

    int m = materials[b];
    if (tid < 15) {
        float a = hb1[m * 15 + tid];
        for (int i = 0; i < 27; ++i) a += mi[i] * hw1[(m * 27 + i) * 15 + tid];
        A[tid] = gelu_exact(a);
    }
    __syncthreads();
    if (tid < 18) {
        float a = hb2[m * 18 + tid];
        for (int i = 0; i < 15; ++i) a += A[i] * hw2[(m * 15 + i) * 18 + tid];
        Bf[tid] = gelu_exact(a);
    }
    __syncthreads();
    if (tid == 0) {
        float a = hb3[m];
        for (int i = 0; i < 18; ++i) a += Bf[i] * hw3[m * 18 + i];
        out[b] = a;
    }
}

// ---------------------------------------------------------------------------
extern "C" void kernel_launch(void* const* d_in, const int* in_sizes, int n_in,
                              void* d_out, int out_size, void* d_ws, size_t ws_size,
                              hipStream_t stream) {
    fp in_seq     = (fp)d_in[0];
    fp proj_vars  = (fp)d_in[1];
    fp param_vars = (fp)d_in[2];
    const int* materials = (const int*)d_in[3];
    fp enc_w1 = (fp)d_in[4];
    fp enc_b1 = (fp)d_in[5];
    fp enc_w2 = (fp)d_in[6];
    fp enc_b2 = (fp)d_in[7];
    fp sos    = (fp)d_in[8];
    fp tl_wq  = (fp)d_in[9];
    fp tl_wk  = (fp)d_in[10];
    fp tl_wv  = (fp)d_in[11];
    fp tl_bq  = (fp)d_in[12];
    fp tl_bk  = (fp)d_in[13];
    fp tl_bv  = (fp)d_in[14];
    fp tl_wo  = (fp)d_in[15];
    fp tl_bo  = (fp)d_in[16];
    fp tl_ln1s = (fp)d_in[17];
    fp tl_ln1b = (fp)d_in[18];
    fp tl_ln2s = (fp)d_in[19];
    fp tl_ln2b = (fp)d_in[20];
    fp tl_fw1 = (fp)d_in[21];
    fp tl_fb1 = (fp)d_in[22];
    fp tl_fw2 = (fp)d_in[23];
    fp tl_fb2 = (fp)d_in[24];
    fp pw1 = (fp)d_in[25]; fp pb1 = (fp)d_in[26];
    fp pw2 = (fp)d_in[27]; fp pb2 = (fp)d_in[28];
    fp pw3 = (fp)d_in[29]; fp pb3 = (fp)d_in[30];
    fp pw4 = (fp)d_in[31]; fp pb4 = (fp)d_in[32];
    fp pw5 = (fp)d_in[33]; fp pb5 = (fp)d_in[34];
    fp ipw1 = (fp)d_in[35]; fp ipb1 = (fp)d_in[36];
    fp ipw2 = (fp)d_in[37]; fp ipb2 = (fp)d_in[38];
    fp hw1 = (fp)d_in[39]; fp hb1 = (fp)d_in[40];
    fp hw2 = (fp)d_in[41]; fp hb2 = (fp)d_in[42];
    fp hw3 = (fp)d_in[43]; fp hb3 = (fp)d_in[44];

    // Workspace layout (fp32): x, q, k, v, o — each NTOK*DD floats (16.8 MB)
    float* x = (float*)d_ws;
    float* q = x + (size_t)NTOK * DD;
    float* k = q + (size_t)NTOK * DD;
    float* v = k + (size_t)NTOK * DD;
    float* o = v + (size_t)NTOK * DD;

    k_encode<<<NTOK, 64, 0, stream>>>(in_seq, enc_w1, enc_b1, enc_w2, enc_b2, sos, x);

    for (int l = 0; l < NLAY; ++l) {
        k_qkv<<<NTOK, 64, 0, stream>>>(
            x,
            tl_wq + (size_t)l * DD * DD, tl_wk + (size_t)l * DD * DD, tl_wv + (size_t)l * DD * DD,
            tl_bq + (size_t)l * DD, tl_bk + (size_t)l * DD, tl_bv + (size_t)l * DD,
            q, k, v);
        k_attn<<<BB * NHD * QTILES, 256, 0, stream>>>(q, k, v, o);
        k_oproj_ln<<<NTOK, 64, 0, stream>>>(
            o, x,
            tl_wo + (size_t)l * DD * DD, tl_bo + (size_t)l * DD,
            tl_ln1s + (size_t)l * DD, tl_ln1b + (size_t)l * DD);
        k_ffn_ln<<<NTOK / FTT, 256, 0, stream>>>(
            x,
            tl_fw1 + (size_t)l * DD * DFFC, tl_fb1 + (size_t)l * DFFC,
            tl_fw2 + (size_t)l * DFFC * DD, tl_fb2 + (size_t)l * DD,
            tl_ln2s + (size_t)l * DD, tl_ln2b + (size_t)l * DD);
    }

    k_head<<<BB, 64, 0, stream>>>(
        x, proj_vars, param_vars, materials,
        pw1, pb1, pw2, pb2, pw3, pb3, pw4, pb4, pw5, pb5,
        ipw1, ipb1, ipw2, ipb2,
        hw1, hb1, hw2, hb2, hw3, hb3,
        (float*)d_out);
}

// Round 6
// 1507.508 us; speedup vs baseline: 5.8860x; 1.4786x over previous
//
#include <hip/hip_runtime.h>
#include <hip/hip_bf16.h>
#include <math.h>

// Problem constants
#define BB   64
#define SS   1024
#define S1C  1025
#define DD   64
#define NHD  4
#define NBH  (BB * NHD)      // 256
#define DHD  16
#define DFFC 256
#define NLAY 3
#define NTOK (BB * S1C)
#define SPAD 1056            // padded key/seq length (66 * 16, 33 * 32)
#define QTILES 65            // ceil(1025/16) q tiles
#define KTILES 66            // key tiles covering padded 1056
#define PVCH   33            // PV chunks of 32 keys
#define PSTRIDE 1064         // P^T row stride in bf16 (1056 + 8, 16B-aligned)
#define FTT   16             // tokens per k_ffn_ln / k_qkv block

typedef const float* fp;
typedef __attribute__((ext_vector_type(8))) short bf16x8;
typedef __attribute__((ext_vector_type(4))) float f32x4;

__device__ __forceinline__ float gelu_exact(float x) {
    return 0.5f * x * (1.0f + erff(x * 0.7071067811865475f));
}
__device__ __forceinline__ short f2b(float f) {
    __hip_bfloat16 h = __float2bfloat16(f);
    return *reinterpret_cast<short*>(&h);
}

// ---------------------------------------------------------------------------
// Kernel 0: zero the pad regions of the bf16 q/k/v buffers (keys 1025..1055).
// One block per bh.
// ---------------------------------------------------------------------------
__global__ __launch_bounds__(64) void k_zero(
    short* __restrict__ qb, short* __restrict__ kb, short* __restrict__ vbt)
{
    int bh = blockIdx.x, t = threadIdx.x;
    for (int i = t; i < 31 * 16; i += 64) {        // rows 1025..1055 x 16 el
        int r = i >> 4, c = i & 15;
        size_t idx = ((size_t)bh * SPAD + 1025 + r) * 16 + c;
        qb[idx] = 0; kb[idx] = 0;
    }
    for (int i = t; i < 16 * 31; i += 64) {        // 16 e-rows x cols 1025..1055
        int e = i / 31, c = i % 31;
        vbt[((size_t)bh * 16 + e) * SPAD + 1025 + c] = 0;
    }
}

// ---------------------------------------------------------------------------
// Kernel 1: encoder MLP (1->48 GELU -> 64) + sos concat + positional encoding
// ---------------------------------------------------------------------------
__global__ __launch_bounds__(64) void k_encode(
    fp in_seq, fp enc_w1, fp enc_b1, fp enc_w2, fp enc_b2, fp sos,
    float* __restrict__ x)
{
    int tok = blockIdx.x;
    int b = tok / S1C, s = tok % S1C;
    int d = threadIdx.x;                 // 0..63
    __shared__ float e[48];
    float val;
    if (s == 0) {
        val = sos[d];
    } else {
        float t = in_seq[b * SS + (s - 1)];
        if (d < 48) e[d] = gelu_exact(t * enc_w1[d] + enc_b1[d]);
        __syncthreads();
        float acc = enc_b2[d];
        for (int j = 0; j < 48; ++j) acc += e[j] * enc_w2[j * DD + d];
        val = acc;
    }
    int i2 = (d >> 1) * 2;
    float factor = expf((float)i2 * (-9.210340371976184f / 64.0f)); // -ln(10000)/D
    float ang = (float)s * factor;
    val += (d & 1) ? cosf(ang) : sinf(ang);
    x[(size_t)tok * DD + d] = val;
}

// ---------------------------------------------------------------------------
// Kernel 2: fused Q/K/V projection, 16 tokens per block (256 thr).
// Wave w handles tokens w*4..w*4+3; lane = output dim d. x tile in LDS
// (broadcast reads); weights streamed coalesced, reused across 16 tokens.
// Emits bf16 q,k in [bh][s(pad 1056)][16] and bf16 v transposed [bh][16][s].
// ---------------------------------------------------------------------------
__global__ __launch_bounds__(256) void k_qkv(
    const float* __restrict__ x,
    fp wq, fp wk, fp wv, fp bq, fp bk, fp bv,
    short* __restrict__ qb, short* __restrict__ kb, short* __restrict__ vbt)
{
    int blk = blockIdx.x, t = threadIdx.x;
    int tok0 = blk * FTT;
    int w = t >> 6, d = t & 63;
    __shared__ float xs[FTT][DD];
    #pragma unroll
    for (int i = 0; i < 4; ++i) {
        int idx = i * 256 + t;
        xs[idx >> 6][idx & 63] = x[(size_t)tok0 * DD + idx];
    }
    __syncthreads();

    float aq[4] = {0,0,0,0}, ak[4] = {0,0,0,0}, av[4] = {0,0,0,0};
    for (int j = 0; j < DD; j += 4) {
        float wq0 = wq[(j+0)*DD+d], wq1 = wq[(j+1)*DD+d], wq2 = wq[(j+2)*DD+d], wq3 = wq[(j+3)*DD+d];
        float wk0 = wk[(j+0)*DD+d], wk1 = wk[(j+1)*DD+d], wk2 = wk[(j+2)*DD+d], wk3 = wk[(j+3)*DD+d];
        float wv0 = wv[(j+0)*DD+d], wv1 = wv[(j+1)*DD+d], wv2 = wv[(j+2)*DD+d], wv3 = wv[(j+3)*DD+d];
        #pragma unroll
        for (int tt = 0; tt < 4; ++tt) {
            float4 xv = *(const float4*)&xs[w*4+tt][j];
            aq[tt] += xv.x*wq0 + xv.y*wq1 + xv.z*wq2 + xv.w*wq3;
            ak[tt] += xv.x*wk0 + xv.y*wk1 + xv.z*wk2 + xv.w*wk3;
            av[tt] += xv.x*wv0 + xv.y*wv1 + xv.z*wv2 + xv.w*wv3;
        }
    }
    float bqv = bq[d], bkv = bk[d], bvv = bv[d];
    int h = d >> 4, e = d & 15;
    #pragma unroll
    for (int tt = 0; tt < 4; ++tt) {
        int tok = tok0 + w*4 + tt;
        int b = tok / S1C, s = tok % S1C;
        int bh = b * NHD + h;
        qb[((size_t)bh * SPAD + s) * 16 + e] = f2b(aq[tt] + bqv);
        kb[((size_t)bh * SPAD + s) * 16 + e] = f2b(ak[tt] + bkv);
        vbt[((size_t)bh * 16 + e) * SPAD + s] = f2b(av[tt] + bvv);
    }
}

// ---------------------------------------------------------------------------
// Kernel 3: MFMA attention. One wave (64 thr) per (bh, 16-q-row tile).
// QK^T via mfma_f32_16x16x32_bf16 (dh=16 zero-padded to K=32 in A):
//   pass 1: row max; pass 2: recompute, exp -> bf16 P^T[q][key] in LDS.
// PV: A = V^T fragments (global, contiguous), B = P^T rows (ds_read_b128),
//   K=32 per MFMA, 33 chunks, fp32 accumulate. Output stored transposed
//   (D[e][q]) as float4 per lane into o[b][s][64].
// Layouts (HW-verified per guide): A[m=lane&15][k=quad*8+j],
//   B[n=lane&15][k=quad*8+j], C/D col=lane&15 row=quad*4+reg.
// ---------------------------------------------------------------------------
__global__ __launch_bounds__(64) void k_attn(
    const short* __restrict__ qb, const short* __restrict__ kb,
    const short* __restrict__ vbt, float* __restrict__ o)
{
    int bid  = blockIdx.x;            // bh * QTILES + tile
    int tile = bid % QTILES;
    int bh   = bid / QTILES;
    int b    = bh >> 2, h = bh & 3;
    int l    = threadIdx.x;
    int quad = l >> 4, lo = l & 15;
    int qg0  = tile * 16;

    __shared__ short Psh[16 * PSTRIDE];   // P^T[q][key], bf16, ~34 KB
    __shared__ float dn[16];

    const short* qbase = qb + (size_t)bh * SPAD * 16;
    const short* kbase = kb + (size_t)bh * SPAD * 16;
    const short* vbase = vbt + (size_t)bh * 16 * SPAD;

    // A fragment: Q rows (m = lo), k = quad*8+j ; quads 2,3 are the zero pad.
    bf16x8 aQ = {0,0,0,0,0,0,0,0};
    if (quad < 2)
        aQ = *(const bf16x8*)(qbase + ((size_t)(qg0 + lo)) * 16 + quad * 8);

    // ---- pass 1: QK^T, track per-q row max (raw scores) ----
    float mx[4] = {-3e38f, -3e38f, -3e38f, -3e38f};
    int key0 = lo;                        // this lane's key column offset
    #pragma unroll 4
    for (int kt = 0; kt < KTILES; ++kt) {
        bf16x8 bK = *(const bf16x8*)(kbase + ((size_t)(kt * 16 + lo)) * 16 + (quad & 1) * 8);
        f32x4 c = __builtin_amdgcn_mfma_f32_16x16x32_bf16(aQ, bK, (f32x4){0.f,0.f,0.f,0.f}, 0, 0, 0);
        if (kt * 16 + key0 <= 1024) {
            mx[0] = fmaxf(mx[0], c[0]); mx[1] = fmaxf(mx[1], c[1]);
            mx[2] = fmaxf(mx[2], c[2]); mx[3] = fmaxf(mx[3], c[3]);
        }
    }
    #pragma unroll
    for (int mask = 1; mask < 16; mask <<= 1) {
        mx[0] = fmaxf(mx[0], __shfl_xor(mx[0], mask, 64));
        mx[1] = fmaxf(mx[1], __shfl_xor(mx[1], mask, 64));
        mx[2] = fmaxf(mx[2], __shfl_xor(mx[2], mask, 64));
        mx[3] = fmaxf(mx[3], __shfl_xor(mx[3], mask, 64));
    }

    // ---- pass 2: recompute, exp, store bf16 P^T, accumulate sums ----
    float sm[4] = {0.f, 0.f, 0.f, 0.f};
    #pragma unroll 4
    for (int kt = 0; kt < KTILES; ++kt) {
        bf16x8 bK = *(const bf16x8*)(kbase + ((size_t)(kt * 16 + lo)) * 16 + (quad & 1) * 8);
        f32x4 c = __builtin_amdgcn_mfma_f32_16x16x32_bf16(aQ, bK, (f32x4){0.f,0.f,0.f,0.f}, 0, 0, 0);
        bool valid = (kt * 16 + key0 <= 1024);
        #pragma unroll
        for (int r = 0; r < 4; ++r) {
            float p = valid ? __expf(0.25f * (c[r] - mx[r])) : 0.f;
            sm[r] += p;
            Psh[(quad * 4 + r) * PSTRIDE + kt * 16 + lo] = f2b(p);
        }
    }
    #pragma unroll
    for (int mask = 1; mask < 16; mask <<= 1) {
        sm[0] += __shfl_xor(sm[0], mask, 64);
        sm[1] += __shfl_xor(sm[1], mask, 64);
        sm[2] += __shfl_xor(sm[2], mask, 64);
        sm[3] += __shfl_xor(sm[3], mask, 64);
    }
    if (lo == 0)
        *(float4*)&dn[quad * 4] = make_float4(sm[0], sm[1], sm[2], sm[3]);
    __syncthreads();

    // ---- PV: D[e][q] = sum_key V^T[e][key] * P^T[key->k][q] ----
    f32x4 oc = {0.f, 0.f, 0.f, 0.f};
    #pragma unroll 4
    for (int ch = 0; ch < PVCH; ++ch) {
        bf16x8 aV = *(const bf16x8*)(vbase + (size_t)lo * SPAD + ch * 32 + quad * 8);
        bf16x8 pB = *(const bf16x8*)&Psh[lo * PSTRIDE + ch * 32 + quad * 8];
        oc = __builtin_amdgcn_mfma_f32_16x16x32_bf16(aV, pB, oc, 0, 0, 0);
    }

    int qrow = qg0 + lo;
    if (qrow < S1C) {
        float inv = 1.0f / dn[lo];
        float4 res = make_float4(oc[0] * inv, oc[1] * inv, oc[2] * inv, oc[3] * inv);
        *(float4*)(o + ((size_t)b * S1C + qrow) * DD + h * DHD + quad * 4) = res;
    }
}

// ---------------------------------------------------------------------------
// Kernel 4: out-projection + residual + LayerNorm1. One wave (64 thr)/token.
// ---------------------------------------------------------------------------
__global__ __launch_bounds__(64) void k_oproj_ln(
    const float* __restrict__ o, float* __restrict__ x,
    fp wo, fp bo, fp lns, fp lnb)
{
    int tok = blockIdx.x;
    int d = threadIdx.x;
    __shared__ float os[DD];
    os[d] = o[(size_t)tok * DD + d];
    __syncthreads();
    float acc = bo[d];
    for (int j = 0; j < DD; ++j) acc += os[j] * wo[j * DD + d];
    float t = acc + x[(size_t)tok * DD + d];
    float sum = t;
    for (int off = 32; off > 0; off >>= 1) sum += __shfl_xor(sum, off, 64);
    float mean = sum * (1.0f / 64.0f);
    float c = t - mean;
    float vs = c * c;
    for (int off = 32; off > 0; off >>= 1) vs += __shfl_xor(vs, off, 64);
    float var = vs * (1.0f / 64.0f);
    float y = c / sqrtf(var + 1e-5f) * lns[d] + lnb[d];
    x[(size_t)tok * DD + d] = y;
}

// ---------------------------------------------------------------------------
// Kernel 5: FFN (64 -> 256 GELU -> 64) + residual + LayerNorm2.
// 16 tokens/block, 256 threads, weights reused across tokens.
// ---------------------------------------------------------------------------
__global__ __launch_bounds__(256) void k_ffn_ln(
    float* __restrict__ x,
    fp w1, fp b1, fp w2, fp b2, fp lns, fp lnb)
{
    int blk = blockIdx.x;
    int t = threadIdx.x;
    int tok0 = blk * FTT;
    __shared__ float xs[FTT][68];
    __shared__ float hid[FTT][260];

    #pragma unroll
    for (int i = 0; i < 4; ++i) {
        int idx = i * 256 + t;
        xs[idx >> 6][idx & 63] = x[(size_t)tok0 * DD + idx];
    }
    __syncthreads();

    {
        float acc[FTT];
        #pragma unroll
        for (int tt = 0; tt < FTT; ++tt) acc[tt] = 0.f;
        for (int j = 0; j < DD; j += 4) {
            float w0 = w1[(j + 0) * DFFC + t];
            float w1v = w1[(j + 1) * DFFC + t];
            float w2v = w1[(j + 2) * DFFC + t];
            float w3 = w1[(j + 3) * DFFC + t];
            #pragma unroll
            for (int tt = 0; tt < FTT; ++tt) {
                float4 xv = *(const float4*)&xs[tt][j];
                acc[tt] += xv.x * w0 + xv.y * w1v + xv.z * w2v + xv.w * w3;
            }
        }
        float b1v = b1[t];
        #pragma unroll
        for (int tt = 0; tt < FTT; ++tt) hid[tt][t] = gelu_exact(acc[tt] + b1v);
    }
    __syncthreads();

    int w = t >> 6, d = t & 63;
    float a2[4] = {0.f, 0.f, 0.f, 0.f};
    for (int kk = 0; kk < DFFC; kk += 4) {
        float w0 = w2[(kk + 0) * DD + d];
        float w1v = w2[(kk + 1) * DD + d];
        float w2v = w2[(kk + 2) * DD + d];
        float w3 = w2[(kk + 3) * DD + d];
        #pragma unroll
        for (int i = 0; i < 4; ++i) {
            float4 hv = *(const float4*)&hid[w * 4 + i][kk];
            a2[i] += hv.x * w0 + hv.y * w1v + hv.z * w2v + hv.w * w3;
        }
    }
    float b2v = b2[d], lnsv = lns[d], lnbv = lnb[d];
    #pragma unroll
    for (int i = 0; i < 4; ++i) {
        int tt = w * 4 + i;
        float val = xs[tt][d] + a2[i] + b2v;
        float sum = val;
        for (int off = 32; off > 0; off >>= 1) sum += __shfl_xor(sum, off, 64);
        float mean = sum * (1.0f / 64.0f);
        float c = val - mean;
        float vs = c * c;
        for (int off = 32; off > 0; off >>= 1) vs += __shfl_xor(vs, off, 64);
        float y = c / sqrtf(vs * (1.0f / 64.0f) + 1e-5f) * lnsv + lnbv;
        x[(size_t)(tok0 + tt) * DD + d] = y;
    }
}

// ---------------------------------------------------------------------------
// Kernel 6: head MLPs. One block (64 thr) per batch element.
// ---------------------------------------------------------------------------
__global__ __launch_bounds__(64) void k_head(
    const float* __restrict__ x, fp proj_vars, fp param_vars,
    const int* __restrict__ materials,
    fp pw1, fp pb1, fp pw2, fp pb2, fp pw3, fp pb3,
    fp pw4, fp pb4, fp pw5, fp pb5,
    fp ipw1, fp ipb1, fp ipw2, fp ipb2,
    fp hw1, fp hb1, fp hw2, fp hb2, fp hw3, fp hb3,
    float* __restrict__ out)
{
    int b = blockIdx.x;
    int tid = threadIdx.x;
    __shared__ float A[80], Bf[80], pp[8], mi[32];

    if (tid < 3) A[tid] = proj_vars[b * 3 + tid];
    A[3 + tid] = x[((size_t)b * S1C + 0) * DD + tid];
    __syncthreads();

    if (tid < 34) {
        float a = pb1[tid];
        for (int i = 0; i < 67; ++i) a += A[i] * pw1[i * 34 + tid];
        Bf[tid] = gelu_exact(a);
    }
    __syncthreads();
    if (tid < 11) {
        float a = pb2[tid];
        for (int i = 0; i < 34; ++i) a += Bf[i] * pw2[i * 11 + tid];
        A[tid] = gelu_exact(a);
    }
    __syncthreads();
    if (tid < 36) {
        float a = pb3[tid];
        for (int i = 0; i < 11; ++i) a += A[i] * pw3[i * 36 + tid];
        Bf[tid] = gelu_exact(a);
    }
    __syncthreads();
    if (tid < 22) {
        float a = pb4[tid];
        for (int i = 0; i < 36; ++i) a += Bf[i] * pw4[i * 22 + tid];
        A[tid] = gelu_exact(a);
    }
    __syncthreads();
    if (tid < 24) {
        float a = pb5[tid];
        for (int i = 0; i < 22; ++i) a += A[i] * pw5[i * 24 + tid];
        mi[3 + tid] = a;
    }
    if (tid < 3) {
        float a = ipb1[tid];
        for (int i = 0; i < 3; ++i) a += param_vars[b * 3 + i] * ipw1[i * 3 + tid];
        pp[tid] = gelu_exact(a);
    }
    __syncthreads();
    if (tid < 3) {
        float a = ipb2[tid];
        for (int i = 0; i < 3; ++i) a += pp[i] * ipw2[i * 3 + tid];
        mi[tid] = a;
    }
    __syncthreads();

    int m = materials[b];
    if (tid < 15) {
        float a = hb1[m * 15 + tid];
        for (int i = 0; i < 27; ++i) a += mi[i] * hw1[(m * 27 + i) * 15 + tid];
        A[tid] = gelu_exact(a);
    }
    __syncthreads();
    if (tid < 18) {
        float a = hb2[m * 18 + tid];
        for (int i = 0; i < 15; ++i) a += A[i] * hw2[(m * 15 + i) * 18 + tid];
        Bf[tid] = gelu_exact(a);
    }
    __syncthreads();
    if (tid == 0) {
        float a = hb3[m];
        for (int i = 0; i < 18; ++i) a += Bf[i] * hw3[m * 18 + i];
        out[b] = a;
    }
}

// ---------------------------------------------------------------------------
extern "C" void kernel_launch(void* const* d_in, const int* in_sizes, int n_in,
                              void* d_out, int out_size, void* d_ws, size_t ws_size,
                              hipStream_t stream) {
    fp in_seq     = (fp)d_in[0];
    fp proj_vars  = (fp)d_in[1];
    fp param_vars = (fp)d_in[2];
    const int* materials = (const int*)d_in[3];
    fp enc_w1 = (fp)d_in[4];
    fp enc_b1 = (fp)d_in[5];
    fp enc_w2 = (fp)d_in[6];
    fp enc_b2 = (fp)d_in[7];
    fp sos    = (fp)d_in[8];
    fp tl_wq  = (fp)d_in[9];
    fp tl_wk  = (fp)d_in[10];
    fp tl_wv  = (fp)d_in[11];
    fp tl_bq  = (fp)d_in[12];
    fp tl_bk  = (fp)d_in[13];
    fp tl_bv  = (fp)d_in[14];
    fp tl_wo  = (fp)d_in[15];
    fp tl_bo  = (fp)d_in[16];
    fp tl_ln1s = (fp)d_in[17];
    fp tl_ln1b = (fp)d_in[18];
    fp tl_ln2s = (fp)d_in[19];
    fp tl_ln2b = (fp)d_in[20];
    fp tl_fw1 = (fp)d_in[21];
    fp tl_fb1 = (fp)d_in[22];
    fp tl_fw2 = (fp)d_in[23];
    fp tl_fb2 = (fp)d_in[24];
    fp pw1 = (fp)d_in[25]; fp pb1 = (fp)d_in[26];
    fp pw2 = (fp)d_in[27]; fp pb2 = (fp)d_in[28];
    fp pw3 = (fp)d_in[29]; fp pb3 = (fp)d_in[30];
    fp pw4 = (fp)d_in[31]; fp pb4 = (fp)d_in[32];
    fp pw5 = (fp)d_in[33]; fp pb5 = (fp)d_in[34];
    fp ipw1 = (fp)d_in[35]; fp ipb1 = (fp)d_in[36];
    fp ipw2 = (fp)d_in[37]; fp ipb2 = (fp)d_in[38];
    fp hw1 = (fp)d_in[39]; fp hb1 = (fp)d_in[40];
    fp hw2 = (fp)d_in[41]; fp hb2 = (fp)d_in[42];
    fp hw3 = (fp)d_in[43]; fp hb3 = (fp)d_in[44];

    // Workspace: x, o fp32 (NTOK*64 each); qb, kb bf16 [bh][1056][16]; vbt bf16 [bh][16][1056]
    float* x = (float*)d_ws;
    float* o = x + (size_t)NTOK * DD;
    short* qb = (short*)(o + (size_t)NTOK * DD);
    short* kb = qb + (size_t)NBH * SPAD * 16;
    short* vbt = kb + (size_t)NBH * SPAD * 16;

    k_zero<<<NBH, 64, 0, stream>>>(qb, kb, vbt);
    k_encode<<<NTOK, 64, 0, stream>>>(in_seq, enc_w1, enc_b1, enc_w2, enc_b2, sos, x);

    for (int l = 0; l < NLAY; ++l) {
        k_qkv<<<NTOK / FTT, 256, 0, stream>>>(
            x,
            tl_wq + (size_t)l * DD * DD, tl_wk + (size_t)l * DD * DD, tl_wv + (size_t)l * DD * DD,
            tl_bq + (size_t)l * DD, tl_bk + (size_t)l * DD, tl_bv + (size_t)l * DD,
            qb, kb, vbt);
        k_attn<<<NBH * QTILES, 64, 0, stream>>>(qb, kb, vbt, o);
        k_oproj_ln<<<NTOK, 64, 0, stream>>>(
            o, x,
            tl_wo + (size_t)l * DD * DD, tl_bo + (size_t)l * DD,
            tl_ln1s + (size_t)l * DD, tl_ln1b + (size_t)l * DD);
        k_ffn_ln<<<NTOK / FTT, 256, 0, stream>>>(
            x,
            tl_fw1 + (size_t)l * DD * DFFC, tl_fb1 + (size_t)l * DFFC,
            tl_fw2 + (size_t)l * DFFC * DD, tl_fb2 + (size_t)l * DD,
            tl_ln2s + (size_t)l * DD, tl_ln2b + (size_t)l * DD);
    }

    k_head<<<BB, 64, 0, stream>>>(
        x, proj_vars, param_vars, materials,
        pw1, pb1, pw2, pb2, pw3, pb3, pw4, pb4, pw5, pb5,
        ipw1, ipb1, ipw2, ipb2,
        hw1, hb1, hw2, hb2, hw3, hb3,
        (float*)d_out);
}

// Round 7
// 972.195 us; speedup vs baseline: 9.1270x; 1.5506x over previous
//
#include <hip/hip_runtime.h>
#include <hip/hip_bf16.h>
#include <math.h>

// Problem constants
#define BB   64
#define SS   1024
#define S1C  1025
#define DD   64
#define NHD  4
#define NBH  (BB * NHD)      // 256
#define DHD  16
#define DFFC 256
#define NLAY 3
#define NTOK (BB * S1C)
#define SPAD 1056            // padded key/seq length (66 * 16, 33 * 32)
#define PVCH   33            // PV chunks of 32 keys
#define TGRP 17              // q-tile groups per bh (17 * 4 waves = 68 tiles)
#define FTT   16             // tokens per block for qkv/ffn/oproj

typedef const float* fp;
typedef __attribute__((ext_vector_type(8))) short bf16x8;
typedef __attribute__((ext_vector_type(4))) float f32x4;

__device__ __forceinline__ float gelu_exact(float x) {
    return 0.5f * x * (1.0f + erff(x * 0.7071067811865475f));
}
__device__ __forceinline__ short f2b(float f) {
    __hip_bfloat16 h = __float2bfloat16(f);
    return *reinterpret_cast<short*>(&h);
}

// ---------------------------------------------------------------------------
// Kernel 0: zero the pad regions of the bf16 q/k/v buffers (rows 1025..1055).
// ---------------------------------------------------------------------------
__global__ __launch_bounds__(64) void k_zero(
    short* __restrict__ qb, short* __restrict__ kb, short* __restrict__ vbt)
{
    int bh = blockIdx.x, t = threadIdx.x;
    for (int i = t; i < 31 * 16; i += 64) {
        int r = i >> 4, c = i & 15;
        size_t idx = ((size_t)bh * SPAD + 1025 + r) * 16 + c;
        qb[idx] = 0; kb[idx] = 0;
    }
    for (int i = t; i < 16 * 31; i += 64) {
        int e = i / 31, c = i % 31;
        vbt[((size_t)bh * 16 + e) * SPAD + 1025 + c] = 0;
    }
}

// ---------------------------------------------------------------------------
// Kernel 1: encoder MLP (1->48 GELU -> 64) + sos concat + positional encoding
// ---------------------------------------------------------------------------
__global__ __launch_bounds__(64) void k_encode(
    fp in_seq, fp enc_w1, fp enc_b1, fp enc_w2, fp enc_b2, fp sos,
    float* __restrict__ x)
{
    int tok = blockIdx.x;
    int b = tok / S1C, s = tok % S1C;
    int d = threadIdx.x;
    __shared__ float e[48];
    float val;
    if (s == 0) {
        val = sos[d];
    } else {
        float t = in_seq[b * SS + (s - 1)];
        if (d < 48) e[d] = gelu_exact(t * enc_w1[d] + enc_b1[d]);
        __syncthreads();
        float acc = enc_b2[d];
        for (int j = 0; j < 48; ++j) acc += e[j] * enc_w2[j * DD + d];
        val = acc;
    }
    int i2 = (d >> 1) * 2;
    float factor = expf((float)i2 * (-9.210340371976184f / 64.0f));
    float ang = (float)s * factor;
    val += (d & 1) ? cosf(ang) : sinf(ang);
    x[(size_t)tok * DD + d] = val;
}

// ---------------------------------------------------------------------------
// Kernel 2: fused Q/K/V projection, 16 tokens per block (256 thr).
// Emits bf16 q,k in [bh][s(pad 1056)][16] and bf16 v transposed [bh][16][s].
// ---------------------------------------------------------------------------
__global__ __launch_bounds__(256) void k_qkv(
    const float* __restrict__ x,
    fp wq, fp wk, fp wv, fp bq, fp bk, fp bv,
    short* __restrict__ qb, short* __restrict__ kb, short* __restrict__ vbt)
{
    int blk = blockIdx.x, t = threadIdx.x;
    int tok0 = blk * FTT;
    int w = t >> 6, d = t & 63;
    __shared__ float xs[FTT][DD];
    #pragma unroll
    for (int i = 0; i < 4; ++i) {
        int idx = i * 256 + t;
        xs[idx >> 6][idx & 63] = x[(size_t)tok0 * DD + idx];
    }
    __syncthreads();

    float aq[4] = {0,0,0,0}, ak[4] = {0,0,0,0}, av[4] = {0,0,0,0};
    for (int j = 0; j < DD; j += 4) {
        float wq0 = wq[(j+0)*DD+d], wq1 = wq[(j+1)*DD+d], wq2 = wq[(j+2)*DD+d], wq3 = wq[(j+3)*DD+d];
        float wk0 = wk[(j+0)*DD+d], wk1 = wk[(j+1)*DD+d], wk2 = wk[(j+2)*DD+d], wk3 = wk[(j+3)*DD+d];
        float wv0 = wv[(j+0)*DD+d], wv1 = wv[(j+1)*DD+d], wv2 = wv[(j+2)*DD+d], wv3 = wv[(j+3)*DD+d];
        #pragma unroll
        for (int tt = 0; tt < 4; ++tt) {
            float4 xv = *(const float4*)&xs[w*4+tt][j];
            aq[tt] += xv.x*wq0 + xv.y*wq1 + xv.z*wq2 + xv.w*wq3;
            ak[tt] += xv.x*wk0 + xv.y*wk1 + xv.z*wk2 + xv.w*wk3;
            av[tt] += xv.x*wv0 + xv.y*wv1 + xv.z*wv2 + xv.w*wv3;
        }
    }
    float bqv = bq[d], bkv = bk[d], bvv = bv[d];
    int h = d >> 4, e = d & 15;
    #pragma unroll
    for (int tt = 0; tt < 4; ++tt) {
        int tok = tok0 + w*4 + tt;
        int b = tok / S1C, s = tok % S1C;
        int bh = b * NHD + h;
        qb[((size_t)bh * SPAD + s) * 16 + e] = f2b(aq[tt] + bqv);
        kb[((size_t)bh * SPAD + s) * 16 + e] = f2b(ak[tt] + bkv);
        vbt[((size_t)bh * 16 + e) * SPAD + s] = f2b(av[tt] + bvv);
    }
}

// ---------------------------------------------------------------------------
// Kernel 3: single-pass flash MFMA attention.
// Block = 256 thr = 4 independent waves; wave w owns q-tile grp*4+w of bh.
// Per 32-key chunk: 2 QK MFMAs -> exp (no max shift; scores are O(1)) ->
// transpose P chunk through per-wave LDS (padded, 2-way alias only) ->
// 1 PV MFMA (reg accumulate). No __syncthreads (wave-internal lgkmcnt only).
// Softmax denominator accumulated per lane, shuffle-reduced at the end.
// Layouts (HW-verified): A[m=lane&15][k=quad*8+j], B[n=lane&15][k=quad*8+j],
// C/D col=lane&15, row=quad*4+reg.
// ---------------------------------------------------------------------------
__global__ __launch_bounds__(256) void k_attn(
    const short* __restrict__ qb, const short* __restrict__ kb,
    const short* __restrict__ vbt, float* __restrict__ o)
{
    int bid = blockIdx.x;            // bh * TGRP + grp
    int grp = bid % TGRP;
    int bh  = bid / TGRP;
    int b = bh >> 2, h = bh & 3;
    int t = threadIdx.x;
    int w = t >> 6, l = t & 63;
    int quad = l >> 4, lo = l & 15;
    int tile = grp * 4 + w;
    if (tile > 64) tile = 64;        // dup of last tile; writes guarded below
    int qg0 = tile * 16;

    __shared__ short pt_all[4][16][40];   // per-wave P^T chunk, stride 40 shorts
    __shared__ float dn_all[4][16];
    short (*pt)[40] = pt_all[w];
    float* dn = dn_all[w];

    const short* qbase = qb + (size_t)bh * SPAD * 16;
    const short* kbase = kb + (size_t)bh * SPAD * 16;
    const short* vbase = vbt + (size_t)bh * 16 * SPAD;

    // A fragment: Q rows (m = lo); quads 2,3 are the K=32 zero pad.
    bf16x8 aQ = {0,0,0,0,0,0,0,0};
    if (quad < 2)
        aQ = *(const bf16x8*)(qbase + ((size_t)(qg0 + lo)) * 16 + quad * 8);

    f32x4 oc = {0.f, 0.f, 0.f, 0.f};
    float sm[4] = {0.f, 0.f, 0.f, 0.f};

    for (int ch = 0; ch < PVCH; ++ch) {
        #pragma unroll
        for (int t01 = 0; t01 < 2; ++t01) {
            int krow = ch * 32 + t01 * 16 + lo;
            bf16x8 bK = *(const bf16x8*)(kbase + (size_t)krow * 16 + (quad & 1) * 8);
            f32x4 c = __builtin_amdgcn_mfma_f32_16x16x32_bf16(
                aQ, bK, (f32x4){0.f,0.f,0.f,0.f}, 0, 0, 0);
            bool valid = (krow <= 1024);
            #pragma unroll
            for (int r = 0; r < 4; ++r) {
                float p = valid ? __expf(0.25f * c[r]) : 0.f;
                sm[r] += p;
                pt[quad * 4 + r][t01 * 16 + lo] = f2b(p);
            }
        }
        bf16x8 aV = *(const bf16x8*)(vbase + (size_t)lo * SPAD + ch * 32 + quad * 8);
        bf16x8 pB = *(const bf16x8*)&pt[lo][quad * 8];
        oc = __builtin_amdgcn_mfma_f32_16x16x32_bf16(aV, pB, oc, 0, 0, 0);
    }

    // denominator: reduce over the 16 key-lanes (lo) within each quad
    #pragma unroll
    for (int mask = 1; mask < 16; mask <<= 1) {
        sm[0] += __shfl_xor(sm[0], mask, 64);
        sm[1] += __shfl_xor(sm[1], mask, 64);
        sm[2] += __shfl_xor(sm[2], mask, 64);
        sm[3] += __shfl_xor(sm[3], mask, 64);
    }
    if (lo == 0)
        *(float4*)&dn[quad * 4] = make_float4(sm[0], sm[1], sm[2], sm[3]);
    // wave-internal LDS dependency; compiler inserts lgkmcnt wait
    int qrow = qg0 + lo;
    if (qrow < S1C) {
        float inv = 1.0f / dn[lo];
        float4 res = make_float4(oc[0] * inv, oc[1] * inv, oc[2] * inv, oc[3] * inv);
        *(float4*)(o + ((size_t)b * S1C + qrow) * DD + h * DHD + quad * 4) = res;
    }
}

// ---------------------------------------------------------------------------
// Kernel 4: out-projection + residual + LayerNorm1. 16 tokens/block, 256 thr.
// Wave w handles tokens w*4..w*4+3; lane = output dim d; weights reused.
// ---------------------------------------------------------------------------
__global__ __launch_bounds__(256) void k_oproj_ln(
    const float* __restrict__ o, float* __restrict__ x,
    fp wo, fp bo, fp lns, fp lnb)
{
    int blk = blockIdx.x, t = threadIdx.x;
    int tok0 = blk * FTT;
    int w = t >> 6, d = t & 63;
    __shared__ float os[FTT][DD];
    #pragma unroll
    for (int i = 0; i < 4; ++i) {
        int idx = i * 256 + t;
        os[idx >> 6][idx & 63] = o[(size_t)tok0 * DD + idx];
    }
    __syncthreads();

    float acc[4] = {0.f, 0.f, 0.f, 0.f};
    for (int j = 0; j < DD; j += 4) {
        float w0 = wo[(j+0)*DD+d], w1 = wo[(j+1)*DD+d], w2 = wo[(j+2)*DD+d], w3 = wo[(j+3)*DD+d];
        #pragma unroll
        for (int tt = 0; tt < 4; ++tt) {
            float4 ov = *(const float4*)&os[w*4+tt][j];
            acc[tt] += ov.x*w0 + ov.y*w1 + ov.z*w2 + ov.w*w3;
        }
    }
    float bov = bo[d], lnsv = lns[d], lnbv = lnb[d];
    #pragma unroll
    for (int tt = 0; tt < 4; ++tt) {
        int tok = tok0 + w*4 + tt;
        float val = acc[tt] + bov + x[(size_t)tok * DD + d];
        float sum = val;
        for (int off = 32; off > 0; off >>= 1) sum += __shfl_xor(sum, off, 64);
        float mean = sum * (1.0f / 64.0f);
        float c = val - mean;
        float vs = c * c;
        for (int off = 32; off > 0; off >>= 1) vs += __shfl_xor(vs, off, 64);
        float y = c / sqrtf(vs * (1.0f / 64.0f) + 1e-5f) * lnsv + lnbv;
        x[(size_t)tok * DD + d] = y;
    }
}

// ---------------------------------------------------------------------------
// Kernel 5: FFN (64 -> 256 GELU -> 64) + residual + LayerNorm2.
// 16 tokens/block, 256 threads, weights reused across tokens.
// ---------------------------------------------------------------------------
__global__ __launch_bounds__(256) void k_ffn_ln(
    float* __restrict__ x,
    fp w1, fp b1, fp w2, fp b2, fp lns, fp lnb)
{
    int blk = blockIdx.x;
    int t = threadIdx.x;
    int tok0 = blk * FTT;
    __shared__ float xs[FTT][68];
    __shared__ float hid[FTT][260];

    #pragma unroll
    for (int i = 0; i < 4; ++i) {
        int idx = i * 256 + t;
        xs[idx >> 6][idx & 63] = x[(size_t)tok0 * DD + idx];
    }
    __syncthreads();

    {
        float acc[FTT];
        #pragma unroll
        for (int tt = 0; tt < FTT; ++tt) acc[tt] = 0.f;
        for (int j = 0; j < DD; j += 4) {
            float w0 = w1[(j + 0) * DFFC + t];
            float w1v = w1[(j + 1) * DFFC + t];
            float w2v = w1[(j + 2) * DFFC + t];
            float w3 = w1[(j + 3) * DFFC + t];
            #pragma unroll
            for (int tt = 0; tt < FTT; ++tt) {
                float4 xv = *(const float4*)&xs[tt][j];
                acc[tt] += xv.x * w0 + xv.y * w1v + xv.z * w2v + xv.w * w3;
            }
        }
        float b1v = b1[t];
        #pragma unroll
        for (int tt = 0; tt < FTT; ++tt) hid[tt][t] = gelu_exact(acc[tt] + b1v);
    }
    __syncthreads();

    int w = t >> 6, d = t & 63;
    float a2[4] = {0.f, 0.f, 0.f, 0.f};
    for (int kk = 0; kk < DFFC; kk += 4) {
        float w0 = w2[(kk + 0) * DD + d];
        float w1v = w2[(kk + 1) * DD + d];
        float w2v = w2[(kk + 2) * DD + d];
        float w3 = w2[(kk + 3) * DD + d];
        #pragma unroll
        for (int i = 0; i < 4; ++i) {
            float4 hv = *(const float4*)&hid[w * 4 + i][kk];
            a2[i] += hv.x * w0 + hv.y * w1v + hv.z * w2v + hv.w * w3;
        }
    }
    float b2v = b2[d], lnsv = lns[d], lnbv = lnb[d];
    #pragma unroll
    for (int i = 0; i < 4; ++i) {
        int tt = w * 4 + i;
        float val = xs[tt][d] + a2[i] + b2v;
        float sum = val;
        for (int off = 32; off > 0; off >>= 1) sum += __shfl_xor(sum, off, 64);
        float mean = sum * (1.0f / 64.0f);
        float c = val - mean;
        float vs = c * c;
        for (int off = 32; off > 0; off >>= 1) vs += __shfl_xor(vs, off, 64);
        float y = c / sqrtf(vs * (1.0f / 64.0f) + 1e-5f) * lnsv + lnbv;
        x[(size_t)(tok0 + tt) * DD + d] = y;
    }
}

// ---------------------------------------------------------------------------
// Kernel 6: head MLPs. One block (64 thr) per batch element.
// ---------------------------------------------------------------------------
__global__ __launch_bounds__(64) void k_head(
    const float* __restrict__ x, fp proj_vars, fp param_vars,
    const int* __restrict__ materials,
    fp pw1, fp pb1, fp pw2, fp pb2, fp pw3, fp pb3,
    fp pw4, fp pb4, fp pw5, fp pb5,
    fp ipw1, fp ipb1, fp ipw2, fp ipb2,
    fp hw1, fp hb1, fp hw2, fp hb2, fp hw3, fp hb3,
    float* __restrict__ out)
{
    int b = blockIdx.x;
    int tid = threadIdx.x;
    __shared__ float A[80], Bf[80], pp[8], mi[32];

    if (tid < 3) A[tid] = proj_vars[b * 3 + tid];
    A[3 + tid] = x[((size_t)b * S1C + 0) * DD + tid];
    __syncthreads();

    if (tid < 34) {
        float a = pb1[tid];
        for (int i = 0; i < 67; ++i) a += A[i] * pw1[i * 34 + tid];
        Bf[tid] = gelu_exact(a);
    }
    __syncthreads();
    if (tid < 11) {
        float a = pb2[tid];
        for (int i = 0; i < 34; ++i) a += Bf[i] * pw2[i * 11 + tid];
        A[tid] = gelu_exact(a);
    }
    __syncthreads();
    if (tid < 36) {
        float a = pb3[tid];
        for (int i = 0; i < 11; ++i) a += A[i] * pw3[i * 36 + tid];
        Bf[tid] = gelu_exact(a);
    }
    __syncthreads();
    if (tid < 22) {
        float a = pb4[tid];
        for (int i = 0; i < 36; ++i) a += Bf[i] * pw4[i * 22 + tid];
        A[tid] = gelu_exact(a);
    }
    __syncthreads();
    if (tid < 24) {
        float a = pb5[tid];
        for (int i = 0; i < 22; ++i) a += A[i] * pw5[i * 24 + tid];
        mi[3 + tid] = a;
    }
    if (tid < 3) {
        float a = ipb1[tid];
        for (int i = 0; i < 3; ++i) a += param_vars[b * 3 + i] * ipw1[i * 3 + tid];
        pp[tid] = gelu_exact(a);
    }
    __syncthreads();
    if (tid < 3) {
        float a = ipb2[tid];
        for (int i = 0; i < 3; ++i) a += pp[i] * ipw2[i * 3 + tid];
        mi[tid] = a;
    }
    __syncthreads();

    int m = materials[b];
    if (tid < 15) {
        float a = hb1[m * 15 + tid];
        for (int i = 0; i < 27; ++i) a += mi[i] * hw1[(m * 27 + i) * 15 + tid];
        A[tid] = gelu_exact(a);
    }
    __syncthreads();
    if (tid < 18) {
        float a = hb2[m * 18 + tid];
        for (int i = 0; i < 15; ++i) a += A[i] * hw2[(m * 15 + i) * 18 + tid];
        Bf[tid] = gelu_exact(a);
    }
    __syncthreads();
    if (tid == 0) {
        float a = hb3[m];
        for (int i = 0; i < 18; ++i) a += Bf[i] * hw3[m * 18 + i];
        out[b] = a;
    }
}

// ---------------------------------------------------------------------------
extern "C" void kernel_launch(void* const* d_in, const int* in_sizes, int n_in,
                              void* d_out, int out_size, void* d_ws, size_t ws_size,
                              hipStream_t stream) {
    fp in_seq     = (fp)d_in[0];
    fp proj_vars  = (fp)d_in[1];
    fp param_vars = (fp)d_in[2];
    const int* materials = (const int*)d_in[3];
    fp enc_w1 = (fp)d_in[4];
    fp enc_b1 = (fp)d_in[5];
    fp enc_w2 = (fp)d_in[6];
    fp enc_b2 = (fp)d_in[7];
    fp sos    = (fp)d_in[8];
    fp tl_wq  = (fp)d_in[9];
    fp tl_wk  = (fp)d_in[10];
    fp tl_wv  = (fp)d_in[11];
    fp tl_bq  = (fp)d_in[12];
    fp tl_bk  = (fp)d_in[13];
    fp tl_bv  = (fp)d_in[14];
    fp tl_wo  = (fp)d_in[15];
    fp tl_bo  = (fp)d_in[16];
    fp tl_ln1s = (fp)d_in[17];
    fp tl_ln1b = (fp)d_in[18];
    fp tl_ln2s = (fp)d_in[19];
    fp tl_ln2b = (fp)d_in[20];
    fp tl_fw1 = (fp)d_in[21];
    fp tl_fb1 = (fp)d_in[22];
    fp tl_fw2 = (fp)d_in[23];
    fp tl_fb2 = (fp)d_in[24];
    fp pw1 = (fp)d_in[25]; fp pb1 = (fp)d_in[26];
    fp pw2 = (fp)d_in[27]; fp pb2 = (fp)d_in[28];
    fp pw3 = (fp)d_in[29]; fp pb3 = (fp)d_in[30];
    fp pw4 = (fp)d_in[31]; fp pb4 = (fp)d_in[32];
    fp pw5 = (fp)d_in[33]; fp pb5 = (fp)d_in[34];
    fp ipw1 = (fp)d_in[35]; fp ipb1 = (fp)d_in[36];
    fp ipw2 = (fp)d_in[37]; fp ipb2 = (fp)d_in[38];
    fp hw1 = (fp)d_in[39]; fp hb1 = (fp)d_in[40];
    fp hw2 = (fp)d_in[41]; fp hb2 = (fp)d_in[42];
    fp hw3 = (fp)d_in[43]; fp hb3 = (fp)d_in[44];

    // Workspace: x, o fp32 (NTOK*64 each); qb, kb bf16 [bh][1056][16]; vbt bf16 [bh][16][1056]
    float* x = (float*)d_ws;
    float* o = x + (size_t)NTOK * DD;
    short* qb = (short*)(o + (size_t)NTOK * DD);
    short* kb = qb + (size_t)NBH * SPAD * 16;
    short* vbt = kb + (size_t)NBH * SPAD * 16;

    k_zero<<<NBH, 64, 0, stream>>>(qb, kb, vbt);
    k_encode<<<NTOK, 64, 0, stream>>>(in_seq, enc_w1, enc_b1, enc_w2, enc_b2, sos, x);

    for (int l = 0; l < NLAY; ++l) {
        k_qkv<<<NTOK / FTT, 256, 0, stream>>>(
            x,
            tl_wq + (size_t)l * DD * DD, tl_wk + (size_t)l * DD * DD, tl_wv + (size_t)l * DD * DD,
            tl_bq + (size_t)l * DD, tl_bk + (size_t)l * DD, tl_bv + (size_t)l * DD,
            qb, kb, vbt);
        k_attn<<<NBH * TGRP, 256, 0, stream>>>(qb, kb, vbt, o);
        k_oproj_ln<<<NTOK / FTT, 256, 0, stream>>>(
            o, x,
            tl_wo + (size_t)l * DD * DD, tl_bo + (size_t)l * DD,
            tl_ln1s + (size_t)l * DD, tl_ln1b + (size_t)l * DD);
        k_ffn_ln<<<NTOK / FTT, 256, 0, stream>>>(
            x,
            tl_fw1 + (size_t)l * DD * DFFC, tl_fb1 + (size_t)l * DFFC,
            tl_fw2 + (size_t)l * DFFC * DD, tl_fb2 + (size_t)l * DD,
            tl_ln2s + (size_t)l * DD, tl_ln2b + (size_t)l * DD);
    }

    k_head<<<BB, 64, 0, stream>>>(
        x, proj_vars, param_vars, materials,
        pw1, pb1, pw2, pb2, pw3, pb3, pw4, pb4, pw5, pb5,
        ipw1, ipb1, ipw2, ipb2,
        hw1, hb1, hw2, hb2, hw3, hb3,
        (float*)d_out);
}

// Round 8
// 693.558 us; speedup vs baseline: 12.7937x; 1.4018x over previous
//
#include <hip/hip_runtime.h>
#include <hip/hip_bf16.h>
#include <math.h>

// Problem constants
#define BB   64
#define SS   1024
#define S1C  1025
#define DD   64
#define NHD  4
#define NBH  (BB * NHD)      // 256
#define DHD  16
#define DFFC 256
#define NLAY 3
#define NTOK (BB * S1C)      // 65600 = 16 * 4100
#define SPAD 1056            // padded key/seq length (66 * 16, 33 * 32)
#define PVCH   33            // PV chunks of 32 keys
#define TGRP 17              // q-tile groups per bh (17 * 4 waves = 68 tiles)
#define FTT   16             // tokens per block for qkv/ffn/oproj
#define HPAD 264             // hid row stride in shorts
#define OPAD 68              // ot row stride in floats

typedef const float* fp;
typedef __attribute__((ext_vector_type(8))) short bf16x8;
typedef __attribute__((ext_vector_type(4))) float f32x4;

__device__ __forceinline__ float gelu_exact(float x) {
    return 0.5f * x * (1.0f + erff(x * 0.7071067811865475f));
}
__device__ __forceinline__ short f2b(float f) {
    __hip_bfloat16 h = __float2bfloat16(f);
    return *reinterpret_cast<short*>(&h);
}

// ---------------------------------------------------------------------------
// Kernel W: one-shot weight convert+transpose to bf16 [n][k] fragments.
// grid (176, 3): 176*256 = 45056 = 3*4096 (qkv) + 16384 (w1) + 16384 (w2)
// ---------------------------------------------------------------------------
__global__ __launch_bounds__(256) void k_wconv(
    fp wq, fp wk, fp wv, fp w1, fp w2,
    short* __restrict__ wqkvT, short* __restrict__ w1T, short* __restrict__ w2T)
{
    int l = blockIdx.y;
    int i = blockIdx.x * 256 + threadIdx.x;
    if (i < 12288) {
        int p = i >> 12, rem = i & 4095;
        int d = rem >> 6, j = rem & 63;
        fp src = (p == 0 ? wq : p == 1 ? wk : wv) + (size_t)l * 4096;
        wqkvT[((size_t)l * 3 + p) * 4096 + rem] = f2b(src[j * 64 + d]);
    } else if (i < 28672) {
        int rem = i - 12288;
        int n = rem >> 6, j = rem & 63;
        w1T[(size_t)l * 16384 + rem] = f2b(w1[(size_t)l * 16384 + j * 256 + n]);
    } else {
        int rem = i - 28672;
        int n = rem >> 8, j = rem & 255;
        w2T[(size_t)l * 16384 + rem] = f2b(w2[(size_t)l * 16384 + j * 64 + n]);
    }
}

// ---------------------------------------------------------------------------
// Kernel 0: zero the pad regions of the bf16 q/k/v buffers (rows 1025..1055).
// ---------------------------------------------------------------------------
__global__ __launch_bounds__(64) void k_zero(
    short* __restrict__ qb, short* __restrict__ kb, short* __restrict__ vbt)
{
    int bh = blockIdx.x, t = threadIdx.x;
    for (int i = t; i < 31 * 16; i += 64) {
        int r = i >> 4, c = i & 15;
        size_t idx = ((size_t)bh * SPAD + 1025 + r) * 16 + c;
        qb[idx] = 0; kb[idx] = 0;
    }
    for (int i = t; i < 16 * 31; i += 64) {
        int e = i / 31, c = i % 31;
        vbt[((size_t)bh * 16 + e) * SPAD + 1025 + c] = 0;
    }
}

// ---------------------------------------------------------------------------
// Kernel 1: encoder MLP (1->48 GELU -> 64) + sos concat + positional encoding
// Writes fp32 x and bf16 xb.
// ---------------------------------------------------------------------------
__global__ __launch_bounds__(64) void k_encode(
    fp in_seq, fp enc_w1, fp enc_b1, fp enc_w2, fp enc_b2, fp sos,
    float* __restrict__ x, short* __restrict__ xb)
{
    int tok = blockIdx.x;
    int b = tok / S1C, s = tok % S1C;
    int d = threadIdx.x;
    __shared__ float e[48];
    float val;
    if (s == 0) {
        val = sos[d];
    } else {
        float t = in_seq[b * SS + (s - 1)];
        if (d < 48) e[d] = gelu_exact(t * enc_w1[d] + enc_b1[d]);
        __syncthreads();
        float acc = enc_b2[d];
        for (int j = 0; j < 48; ++j) acc += e[j] * enc_w2[j * DD + d];
        val = acc;
    }
    int i2 = (d >> 1) * 2;
    float factor = expf((float)i2 * (-9.210340371976184f / 64.0f));
    float ang = (float)s * factor;
    val += (d & 1) ? cosf(ang) : sinf(ang);
    x[(size_t)tok * DD + d] = val;
    xb[(size_t)tok * DD + d] = f2b(val);
}

// ---------------------------------------------------------------------------
// Kernel 2: MFMA Q/K/V projection. 16 tokens/block, 4 waves; wave = head h.
// A = xb token fragments (global bf16), B = wqkvT [n][k] fragments (global).
// 6 MFMAs/wave (3 proj x K=64). Epilogue scatters per-token to qb/kb/vbt.
// Layouts: A[m=lane&15][k=quad*8+j], B[n=lane&15][k=quad*8+j],
//          C/D col=lane&15(n), row=quad*4+r(m).
// ---------------------------------------------------------------------------
__global__ __launch_bounds__(256) void k_qkv(
    const short* __restrict__ xb, const short* __restrict__ wqkvT,
    fp bq, fp bk, fp bv,
    short* __restrict__ qb, short* __restrict__ kb, short* __restrict__ vbt)
{
    int blk = blockIdx.x, t = threadIdx.x;
    int tok0 = blk * FTT;
    int w = t >> 6, l = t & 63;
    int quad = l >> 4, lo = l & 15;

    bf16x8 a0 = *(const bf16x8*)(xb + ((size_t)(tok0 + lo)) * DD + quad * 8);
    bf16x8 a1 = *(const bf16x8*)(xb + ((size_t)(tok0 + lo)) * DD + 32 + quad * 8);

    int n = w * 16 + lo;     // output dim; head = w, e = lo
    #pragma unroll
    for (int p = 0; p < 3; ++p) {
        const short* wT = wqkvT + (size_t)p * 4096 + (size_t)n * 64;
        bf16x8 b0 = *(const bf16x8*)(wT + quad * 8);
        bf16x8 b1 = *(const bf16x8*)(wT + 32 + quad * 8);
        f32x4 c = __builtin_amdgcn_mfma_f32_16x16x32_bf16(a0, b0, (f32x4){0,0,0,0}, 0, 0, 0);
        c = __builtin_amdgcn_mfma_f32_16x16x32_bf16(a1, b1, c, 0, 0, 0);
        float bias = (p == 0 ? bq : p == 1 ? bk : bv)[n];
        #pragma unroll
        for (int r = 0; r < 4; ++r) {
            int tok = tok0 + quad * 4 + r;
            int b = tok / S1C, s = tok % S1C;
            int bh = b * NHD + w;
            short val = f2b(c[r] + bias);
            if (p == 0)      qb[((size_t)bh * SPAD + s) * 16 + lo] = val;
            else if (p == 1) kb[((size_t)bh * SPAD + s) * 16 + lo] = val;
            else             vbt[((size_t)bh * 16 + lo) * SPAD + s] = val;
        }
    }
}

// ---------------------------------------------------------------------------
// Kernel 3: single-pass flash MFMA attention (unchanged from r6).
// ---------------------------------------------------------------------------
__global__ __launch_bounds__(256) void k_attn(
    const short* __restrict__ qb, const short* __restrict__ kb,
    const short* __restrict__ vbt, float* __restrict__ o)
{
    int bid = blockIdx.x;
    int grp = bid % TGRP;
    int bh  = bid / TGRP;
    int b = bh >> 2, h = bh & 3;
    int t = threadIdx.x;
    int w = t >> 6, l = t & 63;
    int quad = l >> 4, lo = l & 15;
    int tile = grp * 4 + w;
    if (tile > 64) tile = 64;
    int qg0 = tile * 16;

    __shared__ short pt_all[4][16][40];
    __shared__ float dn_all[4][16];
    short (*pt)[40] = pt_all[w];
    float* dn = dn_all[w];

    const short* qbase = qb + (size_t)bh * SPAD * 16;
    const short* kbase = kb + (size_t)bh * SPAD * 16;
    const short* vbase = vbt + (size_t)bh * 16 * SPAD;

    bf16x8 aQ = {0,0,0,0,0,0,0,0};
    if (quad < 2)
        aQ = *(const bf16x8*)(qbase + ((size_t)(qg0 + lo)) * 16 + quad * 8);

    f32x4 oc = {0.f, 0.f, 0.f, 0.f};
    float sm[4] = {0.f, 0.f, 0.f, 0.f};

    for (int ch = 0; ch < PVCH; ++ch) {
        #pragma unroll
        for (int t01 = 0; t01 < 2; ++t01) {
            int krow = ch * 32 + t01 * 16 + lo;
            bf16x8 bK = *(const bf16x8*)(kbase + (size_t)krow * 16 + (quad & 1) * 8);
            f32x4 c = __builtin_amdgcn_mfma_f32_16x16x32_bf16(
                aQ, bK, (f32x4){0.f,0.f,0.f,0.f}, 0, 0, 0);
            bool valid = (krow <= 1024);
            #pragma unroll
            for (int r = 0; r < 4; ++r) {
                float p = valid ? __expf(0.25f * c[r]) : 0.f;
                sm[r] += p;
                pt[quad * 4 + r][t01 * 16 + lo] = f2b(p);
            }
        }
        bf16x8 aV = *(const bf16x8*)(vbase + (size_t)lo * SPAD + ch * 32 + quad * 8);
        bf16x8 pB = *(const bf16x8*)&pt[lo][quad * 8];
        oc = __builtin_amdgcn_mfma_f32_16x16x32_bf16(aV, pB, oc, 0, 0, 0);
    }

    #pragma unroll
    for (int mask = 1; mask < 16; mask <<= 1) {
        sm[0] += __shfl_xor(sm[0], mask, 64);
        sm[1] += __shfl_xor(sm[1], mask, 64);
        sm[2] += __shfl_xor(sm[2], mask, 64);
        sm[3] += __shfl_xor(sm[3], mask, 64);
    }
    if (lo == 0)
        *(float4*)&dn[quad * 4] = make_float4(sm[0], sm[1], sm[2], sm[3]);
    int qrow = qg0 + lo;
    if (qrow < S1C) {
        float inv = 1.0f / dn[lo];
        float4 res = make_float4(oc[0] * inv, oc[1] * inv, oc[2] * inv, oc[3] * inv);
        *(float4*)(o + ((size_t)b * S1C + qrow) * DD + h * DHD + quad * 4) = res;
    }
}

// ---------------------------------------------------------------------------
// Kernel 4: out-projection + residual + LayerNorm1. 16 tokens/block, 256 thr.
// Also emits bf16 xb for the next MFMA consumer.
// ---------------------------------------------------------------------------
__global__ __launch_bounds__(256) void k_oproj_ln(
    const float* __restrict__ o, float* __restrict__ x, short* __restrict__ xb,
    fp wo, fp bo, fp lns, fp lnb)
{
    int blk = blockIdx.x, t = threadIdx.x;
    int tok0 = blk * FTT;
    int w = t >> 6, d = t & 63;
    __shared__ float os[FTT][DD];
    #pragma unroll
    for (int i = 0; i < 4; ++i) {
        int idx = i * 256 + t;
        os[idx >> 6][idx & 63] = o[(size_t)tok0 * DD + idx];
    }
    __syncthreads();

    float acc[4] = {0.f, 0.f, 0.f, 0.f};
    for (int j = 0; j < DD; j += 4) {
        float w0 = wo[(j+0)*DD+d], w1 = wo[(j+1)*DD+d], w2 = wo[(j+2)*DD+d], w3 = wo[(j+3)*DD+d];
        #pragma unroll
        for (int tt = 0; tt < 4; ++tt) {
            float4 ov = *(const float4*)&os[w*4+tt][j];
            acc[tt] += ov.x*w0 + ov.y*w1 + ov.z*w2 + ov.w*w3;
        }
    }
    float bov = bo[d], lnsv = lns[d], lnbv = lnb[d];
    #pragma unroll
    for (int tt = 0; tt < 4; ++tt) {
        int tok = tok0 + w*4 + tt;
        float val = acc[tt] + bov + x[(size_t)tok * DD + d];
        float sum = val;
        for (int off = 32; off > 0; off >>= 1) sum += __shfl_xor(sum, off, 64);
        float mean = sum * (1.0f / 64.0f);
        float c = val - mean;
        float vs = c * c;
        for (int off = 32; off > 0; off >>= 1) vs += __shfl_xor(vs, off, 64);
        float y = c / sqrtf(vs * (1.0f / 64.0f) + 1e-5f) * lnsv + lnbv;
        x[(size_t)tok * DD + d] = y;
        xb[(size_t)tok * DD + d] = f2b(y);
    }
}

// ---------------------------------------------------------------------------
// Kernel 5: MFMA FFN (64 -> 256 GELU -> 64) + residual + LayerNorm2.
// 16 tokens/block, 4 waves. Phase1: wave w computes n in [w*64, w*64+64)
// (4 N-tiles x K=64 = 8 MFMAs), gelu in regs, bf16 hid -> LDS.
// Phase2: out n-tile w (K=256 = 8 MFMAs from LDS hid + global w2T).
// Epilogue: residual + LN in fp32 (as before), writes x and xb.
// ---------------------------------------------------------------------------
__global__ __launch_bounds__(256) void k_ffn_ln(
    const short* __restrict__ xbin, float* __restrict__ x, short* __restrict__ xb,
    const short* __restrict__ w1T, fp b1, const short* __restrict__ w2T, fp b2,
    fp lns, fp lnb)
{
    int blk = blockIdx.x, t = threadIdx.x;
    int tok0 = blk * FTT;
    int w = t >> 6, l = t & 63;
    int quad = l >> 4, lo = l & 15;

    __shared__ short hid[FTT][HPAD];
    __shared__ float ot[FTT][OPAD];

    // A fragments: 16 tokens x K=64 (shared by both K-chunks' loads)
    bf16x8 a0 = *(const bf16x8*)(xbin + ((size_t)(tok0 + lo)) * DD + quad * 8);
    bf16x8 a1 = *(const bf16x8*)(xbin + ((size_t)(tok0 + lo)) * DD + 32 + quad * 8);

    // ---- phase 1: hid = gelu(x @ w1 + b1), n-range [w*64, w*64+64) ----
    #pragma unroll
    for (int i = 0; i < 4; ++i) {
        int n = w * 64 + i * 16 + lo;
        const short* wT = w1T + (size_t)n * 64;
        bf16x8 b0 = *(const bf16x8*)(wT + quad * 8);
        bf16x8 bb1 = *(const bf16x8*)(wT + 32 + quad * 8);
        f32x4 c = __builtin_amdgcn_mfma_f32_16x16x32_bf16(a0, b0, (f32x4){0,0,0,0}, 0, 0, 0);
        c = __builtin_amdgcn_mfma_f32_16x16x32_bf16(a1, bb1, c, 0, 0, 0);
        float b1v = b1[n];
        #pragma unroll
        for (int r = 0; r < 4; ++r)
            hid[quad * 4 + r][n] = f2b(gelu_exact(c[r] + b1v));
    }
    __syncthreads();

    // ---- phase 2: out n-tile w (dims w*16..w*16+15), K = 256 ----
    f32x4 c2 = {0.f, 0.f, 0.f, 0.f};
    const short* wT2 = w2T + (size_t)(w * 16 + lo) * 256;
    #pragma unroll
    for (int kc = 0; kc < 8; ++kc) {
        bf16x8 a2 = *(const bf16x8*)&hid[lo][kc * 32 + quad * 8];
        bf16x8 b2f = *(const bf16x8*)(wT2 + kc * 32 + quad * 8);
        c2 = __builtin_amdgcn_mfma_f32_16x16x32_bf16(a2, b2f, c2, 0, 0, 0);
    }
    {
        float b2v = b2[w * 16 + lo];
        #pragma unroll
        for (int r = 0; r < 4; ++r)
            ot[quad * 4 + r][w * 16 + lo] = c2[r] + b2v;
    }
    __syncthreads();

    // ---- epilogue: residual + LN (wave w: tokens w*4..w*4+3, lane = d) ----
    int d = l;
    float lnsv = lns[d], lnbv = lnb[d];
    #pragma unroll
    for (int i = 0; i < 4; ++i) {
        int tt = w * 4 + i;
        int tok = tok0 + tt;
        float val = ot[tt][d] + x[(size_t)tok * DD + d];
        float sum = val;
        for (int off = 32; off > 0; off >>= 1) sum += __shfl_xor(sum, off, 64);
        float mean = sum * (1.0f / 64.0f);
        float c = val - mean;
        float vs = c * c;
        for (int off = 32; off > 0; off >>= 1) vs += __shfl_xor(vs, off, 64);
        float y = c / sqrtf(vs * (1.0f / 64.0f) + 1e-5f) * lnsv + lnbv;
        x[(size_t)tok * DD + d] = y;
        xb[(size_t)tok * DD + d] = f2b(y);
    }
}

// ---------------------------------------------------------------------------
// Kernel 6: head MLPs. One block (64 thr) per batch element.
// ---------------------------------------------------------------------------
__global__ __launch_bounds__(64) void k_head(
    const float* __restrict__ x, fp proj_vars, fp param_vars,
    const int* __restrict__ materials,
    fp pw1, fp pb1, fp pw2, fp pb2, fp pw3, fp pb3,
    fp pw4, fp pb4, fp pw5, fp pb5,
    fp ipw1, fp ipb1, fp ipw2, fp ipb2,
    fp hw1, fp hb1, fp hw2, fp hb2, fp hw3, fp hb3,
    float* __restrict__ out)
{
    int b = blockIdx.x;
    int tid = threadIdx.x;
    __shared__ float A[80], Bf[80], pp[8], mi[32];

    if (tid < 3) A[tid] = proj_vars[b * 3 + tid];
    A[3 + tid] = x[((size_t)b * S1C + 0) * DD + tid];
    __syncthreads();

    if (tid < 34) {
        float a = pb1[tid];
        for (int i = 0; i < 67; ++i) a += A[i] * pw1[i * 34 + tid];
        Bf[tid] = gelu_exact(a);
    }
    __syncthreads();
    if (tid < 11) {
        float a = pb2[tid];
        for (int i = 0; i < 34; ++i) a += Bf[i] * pw2[i * 11 + tid];
        A[tid] = gelu_exact(a);
    }
    __syncthreads();
    if (tid < 36) {
        float a = pb3[tid];
        for (int i = 0; i < 11; ++i) a += A[i] * pw3[i * 36 + tid];
        Bf[tid] = gelu_exact(a);
    }
    __syncthreads();
    if (tid < 22) {
        float a = pb4[tid];
        for (int i = 0; i < 36; ++i) a += Bf[i] * pw4[i * 22 + tid];
        A[tid] = gelu_exact(a);
    }
    __syncthreads();
    if (tid < 24) {
        float a = pb5[tid];
        for (int i = 0; i < 22; ++i) a += A[i] * pw5[i * 24 + tid];
        mi[3 + tid] = a;
    }
    if (tid < 3) {
        float a = ipb1[tid];
        for (int i = 0; i < 3; ++i) a += param_vars[b * 3 + i] * ipw1[i * 3 + tid];
        pp[tid] = gelu_exact(a);
    }
    __syncthreads();
    if (tid < 3) {
        float a = ipb2[tid];
        for (int i = 0; i < 3; ++i) a += pp[i] * ipw2[i * 3 + tid];
        mi[tid] = a;
    }
    __syncthreads();

    int m = materials[b];
    if (tid < 15) {
        float a = hb1[m * 15 + tid];
        for (int i = 0; i < 27; ++i) a += mi[i] * hw1[(m * 27 + i) * 15 + tid];
        A[tid] = gelu_exact(a);
    }
    __syncthreads();
    if (tid < 18) {
        float a = hb2[m * 18 + tid];
        for (int i = 0; i < 15; ++i) a += A[i] * hw2[(m * 15 + i) * 18 + tid];
        Bf[tid] = gelu_exact(a);
    }
    __syncthreads();
    if (tid == 0) {
        float a = hb3[m];
        for (int i = 0; i < 18; ++i) a += Bf[i] * hw3[m * 18 + i];
        out[b] = a;
    }
}

// ---------------------------------------------------------------------------
extern "C" void kernel_launch(void* const* d_in, const int* in_sizes, int n_in,
                              void* d_out, int out_size, void* d_ws, size_t ws_size,
                              hipStream_t stream) {
    fp in_seq     = (fp)d_in[0];
    fp proj_vars  = (fp)d_in[1];
    fp param_vars = (fp)d_in[2];
    const int* materials = (const int*)d_in[3];
    fp enc_w1 = (fp)d_in[4];
    fp enc_b1 = (fp)d_in[5];
    fp enc_w2 = (fp)d_in[6];
    fp enc_b2 = (fp)d_in[7];
    fp sos    = (fp)d_in[8];
    fp tl_wq  = (fp)d_in[9];
    fp tl_wk  = (fp)d_in[10];
    fp tl_wv  = (fp)d_in[11];
    fp tl_bq  = (fp)d_in[12];
    fp tl_bk  = (fp)d_in[13];
    fp tl_bv  = (fp)d_in[14];
    fp tl_wo  = (fp)d_in[15];
    fp tl_bo  = (fp)d_in[16];
    fp tl_ln1s = (fp)d_in[17];
    fp tl_ln1b = (fp)d_in[18];
    fp tl_ln2s = (fp)d_in[19];
    fp tl_ln2b = (fp)d_in[20];
    fp tl_fw1 = (fp)d_in[21];
    fp tl_fb1 = (fp)d_in[22];
    fp tl_fw2 = (fp)d_in[23];
    fp tl_fb2 = (fp)d_in[24];
    fp pw1 = (fp)d_in[25]; fp pb1 = (fp)d_in[26];
    fp pw2 = (fp)d_in[27]; fp pb2 = (fp)d_in[28];
    fp pw3 = (fp)d_in[29]; fp pb3 = (fp)d_in[30];
    fp pw4 = (fp)d_in[31]; fp pb4 = (fp)d_in[32];
    fp pw5 = (fp)d_in[33]; fp pb5 = (fp)d_in[34];
    fp ipw1 = (fp)d_in[35]; fp ipb1 = (fp)d_in[36];
    fp ipw2 = (fp)d_in[37]; fp ipb2 = (fp)d_in[38];
    fp hw1 = (fp)d_in[39]; fp hb1 = (fp)d_in[40];
    fp hw2 = (fp)d_in[41]; fp hb2 = (fp)d_in[42];
    fp hw3 = (fp)d_in[43]; fp hb3 = (fp)d_in[44];

    // Workspace: x, o fp32; xb bf16; qb, kb, vbt bf16; transposed weights bf16
    float* x  = (float*)d_ws;
    float* o  = x + (size_t)NTOK * DD;
    short* xb = (short*)(o + (size_t)NTOK * DD);
    short* qb = xb + (size_t)NTOK * DD;
    short* kb = qb + (size_t)NBH * SPAD * 16;
    short* vbt = kb + (size_t)NBH * SPAD * 16;
    short* wqkvT = vbt + (size_t)NBH * 16 * SPAD;   // 3 layers x 3 proj x 4096
    short* w1T = wqkvT + (size_t)NLAY * 3 * 4096;    // 3 x 16384
    short* w2T = w1T + (size_t)NLAY * 16384;         // 3 x 16384

    k_wconv<<<dim3(176, NLAY), 256, 0, stream>>>(
        tl_wq, tl_wk, tl_wv, tl_fw1, tl_fw2, wqkvT, w1T, w2T);
    k_zero<<<NBH, 64, 0, stream>>>(qb, kb, vbt);
    k_encode<<<NTOK, 64, 0, stream>>>(in_seq, enc_w1, enc_b1, enc_w2, enc_b2, sos, x, xb);

    for (int l = 0; l < NLAY; ++l) {
        k_qkv<<<NTOK / FTT, 256, 0, stream>>>(
            xb, wqkvT + (size_t)l * 3 * 4096,
            tl_bq + (size_t)l * DD, tl_bk + (size_t)l * DD, tl_bv + (size_t)l * DD,
            qb, kb, vbt);
        k_attn<<<NBH * TGRP, 256, 0, stream>>>(qb, kb, vbt, o);
        k_oproj_ln<<<NTOK / FTT, 256, 0, stream>>>(
            o, x, xb,
            tl_wo + (size_t)l * DD * DD, tl_bo + (size_t)l * DD,
            tl_ln1s + (size_t)l * DD, tl_ln1b + (size_t)l * DD);
        k_ffn_ln<<<NTOK / FTT, 256, 0, stream>>>(
            xb, x, xb,
            w1T + (size_t)l * 16384, tl_fb1 + (size_t)l * DFFC,
            w2T + (size_t)l * 16384, tl_fb2 + (size_t)l * DD,
            tl_ln2s + (size_t)l * DD, tl_ln2b + (size_t)l * DD);
    }

    k_head<<<BB, 64, 0, stream>>>(
        x, proj_vars, param_vars, materials,
        pw1, pb1, pw2, pb2, pw3, pb3, pw4, pb4, pw5, pb5,
        ipw1, ipb1, ipw2, ipb2,
        hw1, hb1, hw2, hb2, hw3, hb3,
        (float*)d_out);
}